// Round 1
// baseline (3495.805 us; speedup 1.0000x reference)
//
#include <hip/hip_runtime.h>
#include <hip/hip_bf16.h>

#define T_TOK 2048
#define DIM 1024
#define HEADS 8
#define QK_HD 128
#define V_HD 128
#define NOPE 64
#define ROPE 64
#define KV_LORA 256
#define N_EXP 32
#define TOPK 4
#define INTER 512
#define S_LEN 1024
#define KVP_W (HEADS * (NOPE + V_HD))   // 1536

// ---------------- utility kernels ----------------

__launch_bounds__(256)
__global__ void zero_f_k(float* __restrict__ p, int n) {
  for (int i = blockIdx.x * 256 + threadIdx.x; i < n; i += gridDim.x * 256) p[i] = 0.f;
}

__launch_bounds__(64)
__global__ void zero_counters_k(int* __restrict__ counts, int* __restrict__ fill) {
  int i = threadIdx.x;
  if (i < N_EXP) { counts[i] = 0; fill[i] = 0; }
}

// rmsnorm over `width` cols of row `blockIdx.x`
__launch_bounds__(256)
__global__ void rmsnorm_k(const float* __restrict__ x, int in_stride, int width,
                          const float* __restrict__ w, float* __restrict__ out,
                          int out_stride) {
  int row = blockIdx.x;
  const float* xr = x + (size_t)row * in_stride;
  float* orow = out + (size_t)row * out_stride;
  float ss = 0.f;
  for (int i = threadIdx.x; i < width; i += 256) { float v = xr[i]; ss += v * v; }
  #pragma unroll
  for (int off = 32; off; off >>= 1) ss += __shfl_down(ss, off, 64);
  __shared__ float red[4];
  if ((threadIdx.x & 63) == 0) red[threadIdx.x >> 6] = ss;
  __syncthreads();
  if (threadIdx.x == 0) {
    float tot = red[0] + red[1] + red[2] + red[3];
    red[0] = rsqrtf(tot / (float)width + 1e-6f);
  }
  __syncthreads();
  float scale = red[0];
  for (int i = threadIdx.x; i < width; i += 256) orow[i] = xr[i] * scale * w[i];
}

// ---------------- generic 64x64 f32 GEMM: C = A@B (+R) ----------------
// grid: (N/64, M/64). M,N multiples of 64; K multiple of 16.
template <bool RES>
__launch_bounds__(256)
__global__ void gemm64_k(const float* __restrict__ A, const float* __restrict__ B,
                         const float* __restrict__ R, float* __restrict__ C,
                         int N, int K) {
  int m0 = blockIdx.y * 64;
  int n0 = blockIdx.x * 64;
  __shared__ float As[16][68];
  __shared__ float Bs[16][64];
  int tid = threadIdx.x;
  float acc[4][4] = {};
  int r0 = (tid >> 4) << 2;
  int c0 = (tid & 15) << 2;
  int arow = tid >> 4, ak = tid & 15;
  int brow = tid >> 6, bcol = tid & 63;
  for (int k0 = 0; k0 < K; k0 += 16) {
    #pragma unroll
    for (int i = 0; i < 4; i++)
      As[ak][arow + i * 16] = A[(size_t)(m0 + arow + i * 16) * K + k0 + ak];
    #pragma unroll
    for (int i = 0; i < 4; i++)
      Bs[brow + i * 4][bcol] = B[(size_t)(k0 + brow + i * 4) * N + n0 + bcol];
    __syncthreads();
    #pragma unroll
    for (int kk = 0; kk < 16; kk++) {
      float a[4], b[4];
      #pragma unroll
      for (int i = 0; i < 4; i++) a[i] = As[kk][r0 + i];
      #pragma unroll
      for (int j = 0; j < 4; j++) b[j] = Bs[kk][c0 + j];
      #pragma unroll
      for (int i = 0; i < 4; i++)
        #pragma unroll
        for (int j = 0; j < 4; j++) acc[i][j] += a[i] * b[j];
    }
    __syncthreads();
  }
  #pragma unroll
  for (int i = 0; i < 4; i++) {
    size_t row = m0 + r0 + i;
    #pragma unroll
    for (int j = 0; j < 4; j++) {
      float v = acc[i][j];
      if (RES) v += R[row * N + n0 + c0 + j];
      C[row * N + n0 + c0 + j] = v;
    }
  }
}

// ---------------- attention: flash-style, 32-query tiles ----------------
// grid: (S/32, HEADS, B); block 256
__launch_bounds__(256)
__global__ void attn_k(const float* __restrict__ q, const float* __restrict__ kvp,
                       const float* __restrict__ kv, float* __restrict__ o) {
  int qt = blockIdx.x, h = blockIdx.y, b = blockIdx.z;
  __shared__ float qs[32][129];
  __shared__ float ks[32][129];
  __shared__ float vs[32][129];
  __shared__ float ssm[32][33];
  __shared__ float m_s[32], l_s[32], al_s[32];
  int tid = threadIdx.x;
  const float scale = 0.08838834764831845f;  // 128^-0.5
  for (int i = tid; i < 32 * 128; i += 256) {
    int r = i >> 7, d = i & 127;
    size_t t = (size_t)b * S_LEN + qt * 32 + r;
    qs[r][d] = q[t * (HEADS * QK_HD) + h * QK_HD + d] * scale;
  }
  if (tid < 32) { m_s[tid] = -1e30f; l_s[tid] = 0.f; }
  float o_acc[16];
  #pragma unroll
  for (int i = 0; i < 16; i++) o_acc[i] = 0.f;
  int r_o = tid >> 3;          // 0..31
  int cb = (tid & 7) * 16;     // 0..112
  for (int kt = 0; kt <= qt; ++kt) {
    for (int i = tid; i < 32 * 128; i += 256) {
      int r = i >> 7, d = i & 127;
      size_t t = (size_t)b * S_LEN + kt * 32 + r;
      float kval;
      if (d < NOPE) kval = kvp[t * KVP_W + h * (NOPE + V_HD) + d];
      else kval = kv[t * (KV_LORA + ROPE) + KV_LORA + (d - NOPE)];
      ks[r][d] = kval;
      vs[r][d] = kvp[t * KVP_W + h * (NOPE + V_HD) + NOPE + d];
    }
    __syncthreads();
    {
      int r = tid >> 3;
      int c0s = (tid & 7) * 4;
      float acc[4] = {0.f, 0.f, 0.f, 0.f};
      for (int d = 0; d < 128; d++) {
        float qv = qs[r][d];
        #pragma unroll
        for (int j = 0; j < 4; j++) acc[j] += qv * ks[c0s + j][d];
      }
      int qg = qt * 32 + r;
      #pragma unroll
      for (int j = 0; j < 4; j++) {
        int kg = kt * 32 + c0s + j;
        ssm[r][c0s + j] = (kg <= qg) ? acc[j] : -1e30f;
      }
    }
    __syncthreads();
    if (tid < 32) {
      float mo = m_s[tid];
      float mx = mo;
      for (int c = 0; c < 32; c++) mx = fmaxf(mx, ssm[tid][c]);
      float al = __expf(mo - mx);
      float sum = 0.f;
      for (int c = 0; c < 32; c++) {
        float p = __expf(ssm[tid][c] - mx);
        ssm[tid][c] = p;
        sum += p;
      }
      l_s[tid] = l_s[tid] * al + sum;
      m_s[tid] = mx;
      al_s[tid] = al;
    }
    __syncthreads();
    {
      float al = al_s[r_o];
      #pragma unroll
      for (int i = 0; i < 16; i++) o_acc[i] *= al;
      for (int c = 0; c < 32; c++) {
        float p = ssm[r_o][c];
        #pragma unroll
        for (int i = 0; i < 16; i++) o_acc[i] += p * vs[c][cb + i];
      }
    }
    __syncthreads();
  }
  float inv_l = 1.f / l_s[r_o];
  size_t t = (size_t)b * S_LEN + qt * 32 + r_o;
  #pragma unroll
  for (int i = 0; i < 16; i++)
    o[t * (HEADS * V_HD) + h * V_HD + cb + i] = o_acc[i] * inv_l;
}

// ---------------- gate / routing ----------------
__launch_bounds__(256)
__global__ void gate_k(const float* __restrict__ xf, const float* __restrict__ gw,
                       const float* __restrict__ gb, float* __restrict__ tw,
                       int* __restrict__ tidx, int* __restrict__ counts) {
  int t = blockIdx.x;
  __shared__ float xs[DIM];
  __shared__ float part[256];
  __shared__ float sc[N_EXP];
  int tid = threadIdx.x;
  for (int i = tid; i < DIM; i += 256) xs[i] = xf[(size_t)t * DIM + i];
  __syncthreads();
  {
    int e = tid >> 3, p = tid & 7;
    float s = 0.f;
    const float* ge = gw + (size_t)e * DIM + p * 128;
    const float* xp = xs + p * 128;
    for (int d = 0; d < 128; d++) s += xp[d] * ge[d];
    part[tid] = s;
  }
  __syncthreads();
  if (tid < N_EXP) {
    float tot = 0.f;
    for (int p = 0; p < 8; p++) tot += part[tid * 8 + p];
    sc[tid] = 1.f / (1.f + __expf(-tot));
  }
  __syncthreads();
  if (tid == 0) {
    float orig[N_EXP], sb[N_EXP];
    for (int i = 0; i < N_EXP; i++) { orig[i] = sc[i]; sb[i] = orig[i] + gb[i]; }
    float gsc[8];
    for (int g = 0; g < 8; g++) {
      float m1 = -1e30f, m2 = -1e30f;
      for (int j = 0; j < 4; j++) {
        float v = sb[g * 4 + j];
        if (v > m1) { m2 = m1; m1 = v; } else if (v > m2) m2 = v;
      }
      gsc[g] = m1 + m2;
    }
    bool gok[8] = {false, false, false, false, false, false, false, false};
    for (int it = 0; it < 4; it++) {
      int best = 0; float bv = -1e30f;
      for (int g = 0; g < 8; g++)
        if (!gok[g] && gsc[g] >= bv) { bv = gsc[g]; best = g; }
      gok[best] = true;
    }
    bool taken[N_EXP] = {};
    int idx[TOPK]; float wsum = 0.f;
    for (int k = 0; k < TOPK; k++) {
      int best = 0; float bv = -1e30f;
      for (int i = 0; i < N_EXP; i++)
        if (gok[i >> 2] && !taken[i] && sb[i] >= bv) { bv = sb[i]; best = i; }
      taken[best] = true; idx[k] = best; wsum += orig[best];
    }
    float inv = 1.f / (wsum + 1e-20f);
    for (int k = 0; k < TOPK; k++) {
      tidx[t * TOPK + k] = idx[k];
      tw[t * TOPK + k] = orig[idx[k]] * inv;  // ROUTE_SCALE = 1
      atomicAdd(&counts[idx[k]], 1);
    }
  }
}

__global__ void scan_k(const int* __restrict__ counts, int* __restrict__ offs) {
  if (threadIdx.x == 0 && blockIdx.x == 0) {
    int acc = 0;
    for (int e = 0; e < N_EXP; e++) { offs[e] = acc; acc += counts[e]; }
    offs[N_EXP] = acc;
  }
}

__launch_bounds__(256)
__global__ void scatter_k(const int* __restrict__ tidx, const int* __restrict__ offs,
                          int* __restrict__ fill, int* __restrict__ perm) {
  int t = blockIdx.x * 256 + threadIdx.x;
  if (t >= T_TOK) return;
  for (int j = 0; j < TOPK; j++) {
    int e = tidx[t * TOPK + j];
    int pos = atomicAdd(&fill[e], 1);
    perm[offs[e] + pos] = t * TOPK + j;
  }
}

// ---------------- expert FFN up: h = silu(A@w1)*(A@w3), gathered rows ----------------
// grid: (maxRowTiles, N/64, nExperts)
__launch_bounds__(256)
__global__ void ffn_up_k(const float* __restrict__ xf, const float* __restrict__ w1,
                         const float* __restrict__ w3, float* __restrict__ hout,
                         const int* __restrict__ perm, const int* __restrict__ offs,
                         int Mfull, int N) {
  int e = blockIdx.z;
  int base, count;
  if (offs) { base = offs[e]; count = offs[e + 1] - base; }
  else { base = 0; count = Mfull; }
  int m0 = blockIdx.x * 64;
  if (m0 >= count) return;
  int n0 = blockIdx.y * 64;
  const float* W1 = w1 + (size_t)e * DIM * N;
  const float* W3 = w3 + (size_t)e * DIM * N;
  __shared__ float As[16][68];
  __shared__ float B1s[16][64];
  __shared__ float B2s[16][64];
  __shared__ int toks[64];
  int tid = threadIdx.x;
  if (tid < 64) {
    int g = m0 + tid;
    toks[tid] = (g < count) ? (perm ? (perm[base + g] >> 2) : g) : -1;
  }
  __syncthreads();
  float acc1[4][4] = {}, acc2[4][4] = {};
  int r0 = (tid >> 4) << 2, c0 = (tid & 15) << 2;
  int arow = tid >> 4, ak = tid & 15;
  int brow = tid >> 6, bcol = tid & 63;
  for (int k0 = 0; k0 < DIM; k0 += 16) {
    #pragma unroll
    for (int i = 0; i < 4; i++) {
      int tk = toks[arow + i * 16];
      As[ak][arow + i * 16] = (tk >= 0) ? xf[(size_t)tk * DIM + k0 + ak] : 0.f;
    }
    #pragma unroll
    for (int i = 0; i < 4; i++) {
      B1s[brow + i * 4][bcol] = W1[(size_t)(k0 + brow + i * 4) * N + n0 + bcol];
      B2s[brow + i * 4][bcol] = W3[(size_t)(k0 + brow + i * 4) * N + n0 + bcol];
    }
    __syncthreads();
    #pragma unroll
    for (int kk = 0; kk < 16; kk++) {
      float a[4], b1[4], b2[4];
      #pragma unroll
      for (int i = 0; i < 4; i++) a[i] = As[kk][r0 + i];
      #pragma unroll
      for (int j = 0; j < 4; j++) { b1[j] = B1s[kk][c0 + j]; b2[j] = B2s[kk][c0 + j]; }
      #pragma unroll
      for (int i = 0; i < 4; i++)
        #pragma unroll
        for (int j = 0; j < 4; j++) {
          acc1[i][j] += a[i] * b1[j];
          acc2[i][j] += a[i] * b2[j];
        }
    }
    __syncthreads();
  }
  #pragma unroll
  for (int i = 0; i < 4; i++) {
    int g = m0 + r0 + i;
    if (g >= count) continue;
    #pragma unroll
    for (int j = 0; j < 4; j++) {
      float u = acc1[i][j];
      float hval = (u / (1.f + __expf(-u))) * acc2[i][j];
      hout[(size_t)(base + g) * N + n0 + c0 + j] = hval;
    }
  }
}

// ---------------- expert FFN down: y[token] += w * (h @ w2) ----------------
// grid: (maxRowTiles, DIM/64, nExperts)
__launch_bounds__(256)
__global__ void ffn_down_k(const float* __restrict__ hbuf, const float* __restrict__ w2,
                           float* __restrict__ y, const int* __restrict__ perm,
                           const int* __restrict__ offs, const float* __restrict__ tw,
                           int Mfull) {
  int e = blockIdx.z;
  int base, count;
  if (offs) { base = offs[e]; count = offs[e + 1] - base; }
  else { base = 0; count = Mfull; }
  int m0 = blockIdx.x * 64;
  if (m0 >= count) return;
  int n0 = blockIdx.y * 64;
  const float* W2 = w2 + (size_t)e * INTER * DIM;
  __shared__ float As[16][68];
  __shared__ float Bs[16][64];
  int tid = threadIdx.x;
  float acc[4][4] = {};
  int r0 = (tid >> 4) << 2, c0 = (tid & 15) << 2;
  int arow = tid >> 4, ak = tid & 15;
  int brow = tid >> 6, bcol = tid & 63;
  for (int k0 = 0; k0 < INTER; k0 += 16) {
    #pragma unroll
    for (int i = 0; i < 4; i++) {
      int g = m0 + arow + i * 16;
      As[ak][arow + i * 16] =
          (g < count) ? hbuf[(size_t)(base + g) * INTER + k0 + ak] : 0.f;
    }
    #pragma unroll
    for (int i = 0; i < 4; i++)
      Bs[brow + i * 4][bcol] = W2[(size_t)(k0 + brow + i * 4) * DIM + n0 + bcol];
    __syncthreads();
    #pragma unroll
    for (int kk = 0; kk < 16; kk++) {
      float a[4], b[4];
      #pragma unroll
      for (int i = 0; i < 4; i++) a[i] = As[kk][r0 + i];
      #pragma unroll
      for (int j = 0; j < 4; j++) b[j] = Bs[kk][c0 + j];
      #pragma unroll
      for (int i = 0; i < 4; i++)
        #pragma unroll
        for (int j = 0; j < 4; j++) acc[i][j] += a[i] * b[j];
    }
    __syncthreads();
  }
  #pragma unroll
  for (int i = 0; i < 4; i++) {
    int g = m0 + r0 + i;
    if (g >= count) continue;
    int code = perm ? perm[base + g] : ((base + g) << 2);
    int tok = code >> 2;
    float wg = perm ? tw[code] : 1.0f;
    #pragma unroll
    for (int j = 0; j < 4; j++)
      atomicAdd(&y[(size_t)tok * DIM + n0 + c0 + j], wg * acc[i][j]);
  }
}

__launch_bounds__(256)
__global__ void final_add_k(const float* __restrict__ x1, const float* __restrict__ y,
                            float* __restrict__ out, int n) {
  int i = blockIdx.x * 256 + threadIdx.x;
  if (i < n) out[i] = x1[i] + y[i];
}

// ---------------- host launch ----------------
extern "C" void kernel_launch(void* const* d_in, const int* in_sizes, int n_in,
                              void* d_out, int out_size, void* d_ws, size_t ws_size,
                              hipStream_t stream) {
  const float* x        = (const float*)d_in[0];
  const float* norm_attn= (const float*)d_in[1];
  const float* wq       = (const float*)d_in[2];
  const float* wkv_a    = (const float*)d_in[3];
  const float* kv_norm_w= (const float*)d_in[4];
  const float* wkv_b    = (const float*)d_in[5];
  const float* wo       = (const float*)d_in[6];
  const float* norm_moe = (const float*)d_in[7];
  const float* gate_w   = (const float*)d_in[8];
  const float* gate_b   = (const float*)d_in[9];
  const float* ew1      = (const float*)d_in[10];
  const float* ew2      = (const float*)d_in[11];
  const float* ew3      = (const float*)d_in[12];
  const float* sw1      = (const float*)d_in[13];
  const float* sw2      = (const float*)d_in[14];
  const float* sw3      = (const float*)d_in[15];
  float* out = (float*)d_out;

  const size_t T = T_TOK;
  float* ws = (float*)d_ws;
  float* xn   = ws;                       // T*1024 (later reused as xf)
  float* qb   = xn  + T * 1024;           // T*1024 (later reused as y)
  float* kvb  = qb  + T * 1024;           // T*320
  float* cn   = kvb + T * 320;            // T*256
  float* kvp  = cn  + T * 256;            // T*1536
  float* atn  = kvp + T * 1536;           // T*1024
  float* x1   = atn + T * 1024;           // T*1024
  float* hbuf = x1  + T * 1024;           // T*4*512
  float* hs   = hbuf+ T * 2048;           // T*512
  float* twb  = hs  + T * 512;            // T*4
  int*   ib   = (int*)(twb + T * 4);
  int* tidx   = ib;                       // T*4
  int* counts = tidx + T * 4;             // 32
  int* offs   = counts + 32;              // 33
  int* fill   = offs + 33;                // 32
  int* perm   = fill + 32;                // T*4
  float* xf = xn;   // alias: xn dead after q/kv GEMMs
  float* y  = qb;   // alias: q dead after attention

  // ---- MLA ----
  rmsnorm_k<<<T, 256, 0, stream>>>(x, DIM, DIM, norm_attn, xn, DIM);
  gemm64_k<false><<<dim3(1024 / 64, T / 64), 256, 0, stream>>>(xn, wq, nullptr, qb, 1024, DIM);
  gemm64_k<false><<<dim3(320 / 64, T / 64), 256, 0, stream>>>(xn, wkv_a, nullptr, kvb, 320, DIM);
  rmsnorm_k<<<T, 256, 0, stream>>>(kvb, 320, KV_LORA, kv_norm_w, cn, KV_LORA);
  gemm64_k<false><<<dim3(KVP_W / 64, T / 64), 256, 0, stream>>>(cn, wkv_b, nullptr, kvp, KVP_W, KV_LORA);
  attn_k<<<dim3(S_LEN / 32, HEADS, 2), 256, 0, stream>>>(qb, kvp, kvb, atn);
  gemm64_k<true><<<dim3(1024 / 64, T / 64), 256, 0, stream>>>(atn, wo, x, x1, DIM, 1024);

  // ---- MoE ----
  rmsnorm_k<<<T, 256, 0, stream>>>(x1, DIM, DIM, norm_moe, xf, DIM);
  zero_f_k<<<2048, 256, 0, stream>>>(y, T * DIM);
  zero_counters_k<<<1, 64, 0, stream>>>(counts, fill);
  gate_k<<<T, 256, 0, stream>>>(xf, gate_w, gate_b, twb, tidx, counts);
  scan_k<<<1, 1, 0, stream>>>(counts, offs);
  scatter_k<<<(T_TOK + 255) / 256, 256, 0, stream>>>(tidx, offs, fill, perm);
  // routed experts
  ffn_up_k<<<dim3(32, INTER / 64, N_EXP), 256, 0, stream>>>(xf, ew1, ew3, hbuf, perm, offs, 0, INTER);
  ffn_down_k<<<dim3(32, DIM / 64, N_EXP), 256, 0, stream>>>(hbuf, ew2, y, perm, offs, twb, 0);
  // shared expert
  ffn_up_k<<<dim3(T / 64, INTER / 64, 1), 256, 0, stream>>>(xf, sw1, sw3, hs, nullptr, nullptr, T_TOK, INTER);
  ffn_down_k<<<dim3(T / 64, DIM / 64, 1), 256, 0, stream>>>(hs, sw2, y, nullptr, nullptr, nullptr, T_TOK);

  final_add_k<<<(int)((T * DIM + 255) / 256), 256, 0, stream>>>(x1, y, out, (int)(T * DIM));
}

// Round 3
// 1128.825 us; speedup vs baseline: 3.0969x; 3.0969x over previous
//
#include <hip/hip_runtime.h>
#include <hip/hip_bf16.h>

#define T_TOK 2048
#define DIM 1024
#define HEADS 8
#define QK_HD 128
#define V_HD 128
#define NOPE 64
#define ROPE 64
#define KV_LORA 256
#define N_EXP 32
#define TOPK 4
#define INTER 512
#define S_LEN 1024
#define KVP_W (HEADS * (NOPE + V_HD))   // 1536

typedef __attribute__((ext_vector_type(8))) _Float16 f16x8;
typedef __attribute__((ext_vector_type(4))) float f32x4;

__device__ inline unsigned short f2h(float f) {
  union { _Float16 h; unsigned short u; } c;
  c.h = (_Float16)f;
  return c.u;
}
__device__ inline float h2f(unsigned short u) {
  union { _Float16 h; unsigned short u; } c;
  c.u = u;
  return (float)c.h;
}

// ---------------- transpose + f32->f16 convert: dst[n][k] = src[k][n] ----------------
// grid: (N/32, K/32, E), block 256
__launch_bounds__(256)
__global__ void tcvt_k(const float* __restrict__ src, unsigned short* __restrict__ dst,
                       int K, int N) {
  int e = blockIdx.z;
  src += (size_t)e * K * N;
  dst += (size_t)e * K * N;
  int n0 = blockIdx.x * 32, k0 = blockIdx.y * 32;
  __shared__ float ts[32][33];
  int tid = threadIdx.x;
  int r = tid >> 3, c4 = (tid & 7) * 4;
  float4 v = *(const float4*)(src + (size_t)(k0 + r) * N + n0 + c4);
  ts[r][c4] = v.x; ts[r][c4 + 1] = v.y; ts[r][c4 + 2] = v.z; ts[r][c4 + 3] = v.w;
  __syncthreads();
  ushort4 o;
  o.x = f2h(ts[c4][r]);
  o.y = f2h(ts[c4 + 1][r]);
  o.z = f2h(ts[c4 + 2][r]);
  o.w = f2h(ts[c4 + 3][r]);
  *(ushort4*)(dst + (size_t)(n0 + r) * K + k0 + c4) = o;
}

__launch_bounds__(64)
__global__ void zero_counters_k(int* __restrict__ counts, int* __restrict__ fill) {
  int i = threadIdx.x;
  if (i < N_EXP) { counts[i] = 0; fill[i] = 0; }
}

// rmsnorm: f32 in -> f16 out (+ optional f32 out2)
__launch_bounds__(256)
__global__ void rmsnorm_k(const float* __restrict__ x, int in_stride, int width,
                          const float* __restrict__ w, unsigned short* __restrict__ out,
                          float* __restrict__ out2, int out_stride) {
  int row = blockIdx.x;
  const float* xr = x + (size_t)row * in_stride;
  float ss = 0.f;
  for (int i = threadIdx.x; i < width; i += 256) { float v = xr[i]; ss += v * v; }
  #pragma unroll
  for (int off = 32; off; off >>= 1) ss += __shfl_down(ss, off, 64);
  __shared__ float red[4];
  if ((threadIdx.x & 63) == 0) red[threadIdx.x >> 6] = ss;
  __syncthreads();
  if (threadIdx.x == 0) {
    float tot = red[0] + red[1] + red[2] + red[3];
    red[0] = rsqrtf(tot / (float)width + 1e-6f);
  }
  __syncthreads();
  float scale = red[0];
  for (int i = threadIdx.x; i < width; i += 256) {
    float v = xr[i] * scale * w[i];
    out[(size_t)row * out_stride + i] = f2h(v);
    if (out2) out2[(size_t)row * out_stride + i] = v;
  }
}

// ---------------- MFMA f16 TN GEMM: C[M][N] = A[M][K] @ B^T[N][K] (+R) ----------------
// grid: (N/64, M/64), block 256
template <int RES, int OUTH>
__launch_bounds__(256)
__global__ void gemm_bt_k(const unsigned short* __restrict__ A,
                          const unsigned short* __restrict__ B,
                          const float* __restrict__ R, void* __restrict__ Cout,
                          int N, int K) {
  const int n0 = blockIdx.x * 64;
  const int m0 = blockIdx.y * 64;
  __shared__ __align__(16) unsigned short As[64][72];
  __shared__ __align__(16) unsigned short Bs[64][72];
  const int tid = threadIdx.x;
  const int lane = tid & 63, wave = tid >> 6;
  const int quad = lane >> 4, lm = lane & 15;
  const int wm = (wave >> 1) * 32, wn = (wave & 1) * 32;
  f32x4 acc[2][2] = {};
  const int sr = tid >> 2, sc = tid & 3;
  const unsigned short* Ap = A + (size_t)(m0 + sr) * K;
  const unsigned short* Bp = B + (size_t)(n0 + sr) * K;
  for (int k0 = 0; k0 < K; k0 += 64) {
    f16x8 a0 = *(const f16x8*)(Ap + k0 + sc * 8);
    f16x8 a1 = *(const f16x8*)(Ap + k0 + sc * 8 + 32);
    f16x8 b0 = *(const f16x8*)(Bp + k0 + sc * 8);
    f16x8 b1 = *(const f16x8*)(Bp + k0 + sc * 8 + 32);
    __syncthreads();
    *(f16x8*)&As[sr][sc * 8] = a0;
    *(f16x8*)&As[sr][sc * 8 + 32] = a1;
    *(f16x8*)&Bs[sr][sc * 8] = b0;
    *(f16x8*)&Bs[sr][sc * 8 + 32] = b1;
    __syncthreads();
    #pragma unroll
    for (int ks = 0; ks < 2; ks++) {
      f16x8 af0 = *(const f16x8*)&As[wm + lm][ks * 32 + quad * 8];
      f16x8 af1 = *(const f16x8*)&As[wm + 16 + lm][ks * 32 + quad * 8];
      f16x8 bf0 = *(const f16x8*)&Bs[wn + lm][ks * 32 + quad * 8];
      f16x8 bf1 = *(const f16x8*)&Bs[wn + 16 + lm][ks * 32 + quad * 8];
      acc[0][0] = __builtin_amdgcn_mfma_f32_16x16x32_f16(af0, bf0, acc[0][0], 0, 0, 0);
      acc[0][1] = __builtin_amdgcn_mfma_f32_16x16x32_f16(af0, bf1, acc[0][1], 0, 0, 0);
      acc[1][0] = __builtin_amdgcn_mfma_f32_16x16x32_f16(af1, bf0, acc[1][0], 0, 0, 0);
      acc[1][1] = __builtin_amdgcn_mfma_f32_16x16x32_f16(af1, bf1, acc[1][1], 0, 0, 0);
    }
  }
  #pragma unroll
  for (int i = 0; i < 2; i++)
    #pragma unroll
    for (int j = 0; j < 2; j++) {
      int row = m0 + wm + i * 16 + quad * 4;
      int col = n0 + wn + j * 16 + lm;
      #pragma unroll
      for (int r = 0; r < 4; r++) {
        float v = acc[i][j][r];
        if (RES) v += R[(size_t)(row + r) * N + col];
        if (OUTH) ((unsigned short*)Cout)[(size_t)(row + r) * N + col] = f2h(v);
        else ((float*)Cout)[(size_t)(row + r) * N + col] = v;
      }
    }
}

// ---------------- MoE up: h = silu(A@w1^T)*(A@w3^T), gathered token rows ----------------
// grid: (INTER/64, mtiles, E)
__launch_bounds__(256)
__global__ void moe_up_k(const unsigned short* __restrict__ xfb,
                         const unsigned short* __restrict__ w1t,
                         const unsigned short* __restrict__ w3t,
                         unsigned short* __restrict__ hout,
                         const int* __restrict__ perm, const int* __restrict__ offs,
                         int Mfull) {
  const int e = blockIdx.z;
  int base = 0, count = Mfull;
  if (offs) { base = offs[e]; count = offs[e + 1] - base; }
  const int m0 = blockIdx.y * 64;
  if (m0 >= count) return;
  const int n0 = blockIdx.x * 64;
  const unsigned short* W1 = w1t + (size_t)e * (INTER * DIM);
  const unsigned short* W3 = w3t + (size_t)e * (INTER * DIM);
  __shared__ __align__(16) unsigned short As[64][72];
  __shared__ __align__(16) unsigned short B1s[64][72];
  __shared__ __align__(16) unsigned short B2s[64][72];
  __shared__ int toks[64];
  const int tid = threadIdx.x;
  if (tid < 64) {
    int g = m0 + tid;
    toks[tid] = (g < count) ? (perm ? (perm[base + g] >> 2) : g) : -1;
  }
  __syncthreads();
  const int lane = tid & 63, wave = tid >> 6;
  const int quad = lane >> 4, lm = lane & 15;
  const int wm = (wave >> 1) * 32, wn = (wave & 1) * 32;
  f32x4 acc1[2][2] = {};
  f32x4 acc2[2][2] = {};
  const int sr = tid >> 2, sc = tid & 3;
  const int tok = toks[sr];
  const unsigned short* Ap = xfb + (size_t)(tok < 0 ? 0 : tok) * DIM;
  const bool av = (tok >= 0);
  const unsigned short* B1p = W1 + (size_t)(n0 + sr) * DIM;
  const unsigned short* B2p = W3 + (size_t)(n0 + sr) * DIM;
  for (int k0 = 0; k0 < DIM; k0 += 64) {
    f16x8 a0 = {0,0,0,0,0,0,0,0}, a1 = {0,0,0,0,0,0,0,0};
    if (av) {
      a0 = *(const f16x8*)(Ap + k0 + sc * 8);
      a1 = *(const f16x8*)(Ap + k0 + sc * 8 + 32);
    }
    f16x8 b10 = *(const f16x8*)(B1p + k0 + sc * 8);
    f16x8 b11 = *(const f16x8*)(B1p + k0 + sc * 8 + 32);
    f16x8 b20 = *(const f16x8*)(B2p + k0 + sc * 8);
    f16x8 b21 = *(const f16x8*)(B2p + k0 + sc * 8 + 32);
    __syncthreads();
    *(f16x8*)&As[sr][sc * 8] = a0;
    *(f16x8*)&As[sr][sc * 8 + 32] = a1;
    *(f16x8*)&B1s[sr][sc * 8] = b10;
    *(f16x8*)&B1s[sr][sc * 8 + 32] = b11;
    *(f16x8*)&B2s[sr][sc * 8] = b20;
    *(f16x8*)&B2s[sr][sc * 8 + 32] = b21;
    __syncthreads();
    #pragma unroll
    for (int ks = 0; ks < 2; ks++) {
      f16x8 af0 = *(const f16x8*)&As[wm + lm][ks * 32 + quad * 8];
      f16x8 af1 = *(const f16x8*)&As[wm + 16 + lm][ks * 32 + quad * 8];
      f16x8 b1f0 = *(const f16x8*)&B1s[wn + lm][ks * 32 + quad * 8];
      f16x8 b1f1 = *(const f16x8*)&B1s[wn + 16 + lm][ks * 32 + quad * 8];
      f16x8 b2f0 = *(const f16x8*)&B2s[wn + lm][ks * 32 + quad * 8];
      f16x8 b2f1 = *(const f16x8*)&B2s[wn + 16 + lm][ks * 32 + quad * 8];
      acc1[0][0] = __builtin_amdgcn_mfma_f32_16x16x32_f16(af0, b1f0, acc1[0][0], 0, 0, 0);
      acc1[0][1] = __builtin_amdgcn_mfma_f32_16x16x32_f16(af0, b1f1, acc1[0][1], 0, 0, 0);
      acc1[1][0] = __builtin_amdgcn_mfma_f32_16x16x32_f16(af1, b1f0, acc1[1][0], 0, 0, 0);
      acc1[1][1] = __builtin_amdgcn_mfma_f32_16x16x32_f16(af1, b1f1, acc1[1][1], 0, 0, 0);
      acc2[0][0] = __builtin_amdgcn_mfma_f32_16x16x32_f16(af0, b2f0, acc2[0][0], 0, 0, 0);
      acc2[0][1] = __builtin_amdgcn_mfma_f32_16x16x32_f16(af0, b2f1, acc2[0][1], 0, 0, 0);
      acc2[1][0] = __builtin_amdgcn_mfma_f32_16x16x32_f16(af1, b2f0, acc2[1][0], 0, 0, 0);
      acc2[1][1] = __builtin_amdgcn_mfma_f32_16x16x32_f16(af1, b2f1, acc2[1][1], 0, 0, 0);
    }
  }
  #pragma unroll
  for (int i = 0; i < 2; i++)
    #pragma unroll
    for (int j = 0; j < 2; j++) {
      int col = n0 + wn + j * 16 + lm;
      #pragma unroll
      for (int r = 0; r < 4; r++) {
        int g = m0 + wm + i * 16 + quad * 4 + r;
        if (g < count) {
          float u = acc1[i][j][r];
          float vv = acc2[i][j][r];
          float h = (u / (1.f + __expf(-u))) * vv;
          hout[(size_t)(base + g) * INTER + col] = f2h(h);
        }
      }
    }
}

// ---------------- MoE down: dout rows (permuted order) = h @ w2^T ----------------
// grid: (DIM/64, mtiles, E)
__launch_bounds__(256)
__global__ void moe_down_k(const unsigned short* __restrict__ hbuf,
                           const unsigned short* __restrict__ w2t,
                           unsigned short* __restrict__ dout,
                           const int* __restrict__ offs, int Mfull) {
  const int e = blockIdx.z;
  int base = 0, count = Mfull;
  if (offs) { base = offs[e]; count = offs[e + 1] - base; }
  const int m0 = blockIdx.y * 64;
  if (m0 >= count) return;
  const int n0 = blockIdx.x * 64;
  const unsigned short* W2 = w2t + (size_t)e * (DIM * INTER);
  __shared__ __align__(16) unsigned short As[64][72];
  __shared__ __align__(16) unsigned short Bs[64][72];
  const int tid = threadIdx.x;
  const int lane = tid & 63, wave = tid >> 6;
  const int quad = lane >> 4, lm = lane & 15;
  const int wm = (wave >> 1) * 32, wn = (wave & 1) * 32;
  f32x4 acc[2][2] = {};
  const int sr = tid >> 2, sc = tid & 3;
  const int g_s = m0 + sr;
  const bool av = (g_s < count);
  const unsigned short* Ap = hbuf + (size_t)(base + (av ? g_s : 0)) * INTER;
  const unsigned short* Bp = W2 + (size_t)(n0 + sr) * INTER;
  for (int k0 = 0; k0 < INTER; k0 += 64) {
    f16x8 a0 = {0,0,0,0,0,0,0,0}, a1 = {0,0,0,0,0,0,0,0};
    if (av) {
      a0 = *(const f16x8*)(Ap + k0 + sc * 8);
      a1 = *(const f16x8*)(Ap + k0 + sc * 8 + 32);
    }
    f16x8 b0 = *(const f16x8*)(Bp + k0 + sc * 8);
    f16x8 b1 = *(const f16x8*)(Bp + k0 + sc * 8 + 32);
    __syncthreads();
    *(f16x8*)&As[sr][sc * 8] = a0;
    *(f16x8*)&As[sr][sc * 8 + 32] = a1;
    *(f16x8*)&Bs[sr][sc * 8] = b0;
    *(f16x8*)&Bs[sr][sc * 8 + 32] = b1;
    __syncthreads();
    #pragma unroll
    for (int ks = 0; ks < 2; ks++) {
      f16x8 af0 = *(const f16x8*)&As[wm + lm][ks * 32 + quad * 8];
      f16x8 af1 = *(const f16x8*)&As[wm + 16 + lm][ks * 32 + quad * 8];
      f16x8 bf0 = *(const f16x8*)&Bs[wn + lm][ks * 32 + quad * 8];
      f16x8 bf1 = *(const f16x8*)&Bs[wn + 16 + lm][ks * 32 + quad * 8];
      acc[0][0] = __builtin_amdgcn_mfma_f32_16x16x32_f16(af0, bf0, acc[0][0], 0, 0, 0);
      acc[0][1] = __builtin_amdgcn_mfma_f32_16x16x32_f16(af0, bf1, acc[0][1], 0, 0, 0);
      acc[1][0] = __builtin_amdgcn_mfma_f32_16x16x32_f16(af1, bf0, acc[1][0], 0, 0, 0);
      acc[1][1] = __builtin_amdgcn_mfma_f32_16x16x32_f16(af1, bf1, acc[1][1], 0, 0, 0);
    }
  }
  #pragma unroll
  for (int i = 0; i < 2; i++)
    #pragma unroll
    for (int j = 0; j < 2; j++) {
      int col = n0 + wn + j * 16 + lm;
      #pragma unroll
      for (int r = 0; r < 4; r++) {
        int g = m0 + wm + i * 16 + quad * 4 + r;
        if (g < count)
          dout[(size_t)(base + g) * DIM + col] = f2h(acc[i][j][r]);
      }
    }
}

// ---------------- attention: flash-style f32, 32-query tiles, f16 out ----------------
__launch_bounds__(256)
__global__ void attn_k(const float* __restrict__ q, const float* __restrict__ kvp,
                       const float* __restrict__ kv, unsigned short* __restrict__ o) {
  int qt = blockIdx.x, h = blockIdx.y, b = blockIdx.z;
  __shared__ float qs[32][129];
  __shared__ float ks[32][129];
  __shared__ float vs[32][129];
  __shared__ float ssm[32][33];
  __shared__ float m_s[32], l_s[32], al_s[32];
  int tid = threadIdx.x;
  const float scale = 0.08838834764831845f;
  for (int i = tid; i < 32 * 128; i += 256) {
    int r = i >> 7, d = i & 127;
    size_t t = (size_t)b * S_LEN + qt * 32 + r;
    qs[r][d] = q[t * (HEADS * QK_HD) + h * QK_HD + d] * scale;
  }
  if (tid < 32) { m_s[tid] = -1e30f; l_s[tid] = 0.f; }
  float o_acc[16];
  #pragma unroll
  for (int i = 0; i < 16; i++) o_acc[i] = 0.f;
  int r_o = tid >> 3;
  int cb = (tid & 7) * 16;
  for (int kt = 0; kt <= qt; ++kt) {
    for (int i = tid; i < 32 * 128; i += 256) {
      int r = i >> 7, d = i & 127;
      size_t t = (size_t)b * S_LEN + kt * 32 + r;
      float kval;
      if (d < NOPE) kval = kvp[t * KVP_W + h * (NOPE + V_HD) + d];
      else kval = kv[t * (KV_LORA + ROPE) + KV_LORA + (d - NOPE)];
      ks[r][d] = kval;
      vs[r][d] = kvp[t * KVP_W + h * (NOPE + V_HD) + NOPE + d];
    }
    __syncthreads();
    {
      int r = tid >> 3;
      int c0s = (tid & 7) * 4;
      float acc[4] = {0.f, 0.f, 0.f, 0.f};
      for (int d = 0; d < 128; d++) {
        float qv = qs[r][d];
        #pragma unroll
        for (int j = 0; j < 4; j++) acc[j] += qv * ks[c0s + j][d];
      }
      int qg = qt * 32 + r;
      #pragma unroll
      for (int j = 0; j < 4; j++) {
        int kg = kt * 32 + c0s + j;
        ssm[r][c0s + j] = (kg <= qg) ? acc[j] : -1e30f;
      }
    }
    __syncthreads();
    if (tid < 32) {
      float mo = m_s[tid];
      float mx = mo;
      for (int c = 0; c < 32; c++) mx = fmaxf(mx, ssm[tid][c]);
      float al = __expf(mo - mx);
      float sum = 0.f;
      for (int c = 0; c < 32; c++) {
        float p = __expf(ssm[tid][c] - mx);
        ssm[tid][c] = p;
        sum += p;
      }
      l_s[tid] = l_s[tid] * al + sum;
      m_s[tid] = mx;
      al_s[tid] = al;
    }
    __syncthreads();
    {
      float al = al_s[r_o];
      #pragma unroll
      for (int i = 0; i < 16; i++) o_acc[i] *= al;
      for (int c = 0; c < 32; c++) {
        float p = ssm[r_o][c];
        #pragma unroll
        for (int i = 0; i < 16; i++) o_acc[i] += p * vs[c][cb + i];
      }
    }
    __syncthreads();
  }
  float inv_l = 1.f / l_s[r_o];
  size_t t = (size_t)b * S_LEN + qt * 32 + r_o;
  #pragma unroll
  for (int i = 0; i < 16; i++)
    o[t * (HEADS * V_HD) + h * V_HD + cb + i] = f2h(o_acc[i] * inv_l);
}

// ---------------- gate / routing ----------------
__launch_bounds__(256)
__global__ void gate_k(const float* __restrict__ xf, const float* __restrict__ gw,
                       const float* __restrict__ gb, float* __restrict__ tw,
                       int* __restrict__ tidx, int* __restrict__ counts) {
  int t = blockIdx.x;
  __shared__ float xs[DIM];
  __shared__ float part[256];
  __shared__ float sc[N_EXP];
  int tid = threadIdx.x;
  for (int i = tid; i < DIM; i += 256) xs[i] = xf[(size_t)t * DIM + i];
  __syncthreads();
  {
    int e = tid >> 3, p = tid & 7;
    float s = 0.f;
    const float* ge = gw + (size_t)e * DIM + p * 128;
    const float* xp = xs + p * 128;
    for (int d = 0; d < 128; d++) s += xp[d] * ge[d];
    part[tid] = s;
  }
  __syncthreads();
  if (tid < N_EXP) {
    float tot = 0.f;
    for (int p = 0; p < 8; p++) tot += part[tid * 8 + p];
    sc[tid] = 1.f / (1.f + __expf(-tot));
  }
  __syncthreads();
  if (tid == 0) {
    float orig[N_EXP], sb[N_EXP];
    for (int i = 0; i < N_EXP; i++) { orig[i] = sc[i]; sb[i] = orig[i] + gb[i]; }
    float gsc[8];
    for (int g = 0; g < 8; g++) {
      float m1 = -1e30f, m2 = -1e30f;
      for (int j = 0; j < 4; j++) {
        float v = sb[g * 4 + j];
        if (v > m1) { m2 = m1; m1 = v; } else if (v > m2) m2 = v;
      }
      gsc[g] = m1 + m2;
    }
    bool gok[8] = {false, false, false, false, false, false, false, false};
    for (int it = 0; it < 4; it++) {
      int best = 0; float bv = -1e30f;
      for (int g = 0; g < 8; g++)
        if (!gok[g] && gsc[g] >= bv) { bv = gsc[g]; best = g; }
      gok[best] = true;
    }
    bool taken[N_EXP] = {};
    int idx[TOPK]; float wsum = 0.f;
    for (int k = 0; k < TOPK; k++) {
      int best = 0; float bv = -1e30f;
      for (int i = 0; i < N_EXP; i++)
        if (gok[i >> 2] && !taken[i] && sb[i] >= bv) { bv = sb[i]; best = i; }
      taken[best] = true; idx[k] = best; wsum += orig[best];
    }
    float inv = 1.f / (wsum + 1e-20f);
    for (int k = 0; k < TOPK; k++) {
      tidx[t * TOPK + k] = idx[k];
      tw[t * TOPK + k] = orig[idx[k]] * inv;
      atomicAdd(&counts[idx[k]], 1);
    }
  }
}

__global__ void scan_k(const int* __restrict__ counts, int* __restrict__ offs) {
  if (threadIdx.x == 0 && blockIdx.x == 0) {
    int acc = 0;
    for (int e = 0; e < N_EXP; e++) { offs[e] = acc; acc += counts[e]; }
    offs[N_EXP] = acc;
  }
}

__launch_bounds__(256)
__global__ void scatter_k(const int* __restrict__ tidx, const int* __restrict__ offs,
                          int* __restrict__ fill, int* __restrict__ perm,
                          int* __restrict__ posOf) {
  int t = blockIdx.x * 256 + threadIdx.x;
  if (t >= T_TOK) return;
  for (int j = 0; j < TOPK; j++) {
    int e = tidx[t * TOPK + j];
    int pos = atomicAdd(&fill[e], 1);
    int p = offs[e] + pos;
    perm[p] = t * TOPK + j;
    posOf[t * TOPK + j] = p;
  }
}

// ---------------- final combine: out = x1 + shared + sum_j w_j * dbuf[pos_j] ----------------
__launch_bounds__(256)
__global__ void final_gather_k(const float* __restrict__ x1,
                               const unsigned short* __restrict__ dbuf,
                               const unsigned short* __restrict__ sdbuf,
                               const int* __restrict__ posOf,
                               const float* __restrict__ tw,
                               float* __restrict__ out) {
  int t = blockIdx.x;
  int c0 = threadIdx.x * 4;
  int p0 = posOf[t * 4 + 0], p1 = posOf[t * 4 + 1];
  int p2 = posOf[t * 4 + 2], p3 = posOf[t * 4 + 3];
  float w0 = tw[t * 4 + 0], w1 = tw[t * 4 + 1];
  float w2 = tw[t * 4 + 2], w3 = tw[t * 4 + 3];
  size_t tb = (size_t)t * DIM;
  #pragma unroll
  for (int i = 0; i < 4; i++) {
    int c = c0 + i;
    float v = x1[tb + c] + h2f(sdbuf[tb + c])
            + w0 * h2f(dbuf[(size_t)p0 * DIM + c])
            + w1 * h2f(dbuf[(size_t)p1 * DIM + c])
            + w2 * h2f(dbuf[(size_t)p2 * DIM + c])
            + w3 * h2f(dbuf[(size_t)p3 * DIM + c]);
    out[tb + c] = v;
  }
}

// ---------------- host launch ----------------
extern "C" void kernel_launch(void* const* d_in, const int* in_sizes, int n_in,
                              void* d_out, int out_size, void* d_ws, size_t ws_size,
                              hipStream_t stream) {
  const float* x        = (const float*)d_in[0];
  const float* norm_attn= (const float*)d_in[1];
  const float* wq       = (const float*)d_in[2];
  const float* wkv_a    = (const float*)d_in[3];
  const float* kv_norm_w= (const float*)d_in[4];
  const float* wkv_b    = (const float*)d_in[5];
  const float* wo       = (const float*)d_in[6];
  const float* norm_moe = (const float*)d_in[7];
  const float* gate_w   = (const float*)d_in[8];
  const float* gate_b   = (const float*)d_in[9];
  const float* ew1      = (const float*)d_in[10];
  const float* ew2      = (const float*)d_in[11];
  const float* ew3      = (const float*)d_in[12];
  const float* sw1      = (const float*)d_in[13];
  const float* sw2      = (const float*)d_in[14];
  const float* sw3      = (const float*)d_in[15];
  float* out = (float*)d_out;

  char* wp = (char*)d_ws;
  auto alloc = [&](size_t bytes) -> char* {
    char* r = wp;
    wp += (bytes + 255) & ~(size_t)255;
    return r;
  };
  typedef unsigned short us;
  us* wqT   = (us*)alloc(1048576 * 2);
  us* wkvaT = (us*)alloc(327680 * 2);
  us* wkvbT = (us*)alloc(393216 * 2);
  us* woT   = (us*)alloc(1048576 * 2);
  us* ew1T  = (us*)alloc((size_t)16777216 * 2);
  us* ew3T  = (us*)alloc((size_t)16777216 * 2);
  us* ew2T  = (us*)alloc((size_t)16777216 * 2);
  us* sw1T  = (us*)alloc(524288 * 2);
  us* sw3T  = (us*)alloc(524288 * 2);
  us* sw2T  = (us*)alloc(524288 * 2);
  us* xb    = (us*)alloc(2097152 * 2);   // xn, later xfb
  us* cn    = (us*)alloc(524288 * 2);
  us* atn   = (us*)alloc(2097152 * 2);
  us* dbuf  = (us*)alloc((size_t)8388608 * 2);
  float* qb   = (float*)alloc(2097152 * 4);   // later sdbuf (ushort) aliases front
  float* kvb  = (float*)alloc(655360 * 4);
  float* kvp  = (float*)alloc(3145728 * 4);   // later hbuf + hs alias
  float* x1   = (float*)alloc(2097152 * 4);
  float* xf32 = (float*)alloc(2097152 * 4);
  float* twb  = (float*)alloc(8192 * 4);
  int* tidx   = (int*)alloc(8192 * 4);
  int* perm   = (int*)alloc(8192 * 4);
  int* posOf  = (int*)alloc(8192 * 4);
  int* counts = (int*)alloc(64 * 4);
  int* offs   = (int*)alloc(64 * 4);
  int* fill   = (int*)alloc(64 * 4);
  us* sdbuf = (us*)qb;
  us* hbuf  = (us*)kvp;
  us* hs    = hbuf + (size_t)8192 * 512;

  // weight transpose + convert
  tcvt_k<<<dim3(32, 32, 1), 256, 0, stream>>>(wq, wqT, 1024, 1024);
  tcvt_k<<<dim3(10, 32, 1), 256, 0, stream>>>(wkv_a, wkvaT, 1024, 320);
  tcvt_k<<<dim3(48, 8, 1), 256, 0, stream>>>(wkv_b, wkvbT, 256, 1536);
  tcvt_k<<<dim3(32, 32, 1), 256, 0, stream>>>(wo, woT, 1024, 1024);
  tcvt_k<<<dim3(16, 32, 32), 256, 0, stream>>>(ew1, ew1T, 1024, 512);
  tcvt_k<<<dim3(16, 32, 32), 256, 0, stream>>>(ew3, ew3T, 1024, 512);
  tcvt_k<<<dim3(32, 16, 32), 256, 0, stream>>>(ew2, ew2T, 512, 1024);
  tcvt_k<<<dim3(16, 32, 1), 256, 0, stream>>>(sw1, sw1T, 1024, 512);
  tcvt_k<<<dim3(16, 32, 1), 256, 0, stream>>>(sw3, sw3T, 1024, 512);
  tcvt_k<<<dim3(32, 16, 1), 256, 0, stream>>>(sw2, sw2T, 512, 1024);

  // ---- MLA ----
  rmsnorm_k<<<T_TOK, 256, 0, stream>>>(x, DIM, DIM, norm_attn, xb, nullptr, DIM);
  gemm_bt_k<0, 0><<<dim3(16, 32), 256, 0, stream>>>(xb, wqT, nullptr, qb, 1024, 1024);
  gemm_bt_k<0, 0><<<dim3(5, 32), 256, 0, stream>>>(xb, wkvaT, nullptr, kvb, 320, 1024);
  rmsnorm_k<<<T_TOK, 256, 0, stream>>>(kvb, 320, KV_LORA, kv_norm_w, cn, nullptr, KV_LORA);
  gemm_bt_k<0, 0><<<dim3(24, 32), 256, 0, stream>>>(cn, wkvbT, nullptr, kvp, 1536, 256);
  attn_k<<<dim3(S_LEN / 32, HEADS, 2), 256, 0, stream>>>(qb, kvp, kvb, atn);
  gemm_bt_k<1, 0><<<dim3(16, 32), 256, 0, stream>>>(atn, woT, x, x1, 1024, 1024);

  // ---- MoE ----
  rmsnorm_k<<<T_TOK, 256, 0, stream>>>(x1, DIM, DIM, norm_moe, xb, xf32, DIM);
  zero_counters_k<<<1, 64, 0, stream>>>(counts, fill);
  gate_k<<<T_TOK, 256, 0, stream>>>(xf32, gate_w, gate_b, twb, tidx, counts);
  scan_k<<<1, 1, 0, stream>>>(counts, offs);
  scatter_k<<<(T_TOK + 255) / 256, 256, 0, stream>>>(tidx, offs, fill, perm, posOf);
  moe_up_k<<<dim3(8, 32, 32), 256, 0, stream>>>(xb, ew1T, ew3T, hbuf, perm, offs, 0);
  moe_down_k<<<dim3(16, 32, 32), 256, 0, stream>>>(hbuf, ew2T, dbuf, offs, 0);
  moe_up_k<<<dim3(8, 32, 1), 256, 0, stream>>>(xb, sw1T, sw3T, hs, nullptr, nullptr, T_TOK);
  moe_down_k<<<dim3(16, 32, 1), 256, 0, stream>>>(hs, sw2T, sdbuf, nullptr, T_TOK);

  final_gather_k<<<T_TOK, 256, 0, stream>>>(x1, dbuf, sdbuf, posOf, twb, out);
}

// Round 4
// 600.644 us; speedup vs baseline: 5.8201x; 1.8794x over previous
//
#include <hip/hip_runtime.h>
#include <hip/hip_bf16.h>

#define T_TOK 2048
#define DIM 1024
#define HEADS 8
#define QK_HD 128
#define V_HD 128
#define NOPE 64
#define ROPE 64
#define KV_LORA 256
#define N_EXP 32
#define TOPK 4
#define INTER 512
#define S_LEN 1024
#define KVP_W (HEADS * (NOPE + V_HD))   // 1536

typedef __attribute__((ext_vector_type(8))) _Float16 f16x8;
typedef __attribute__((ext_vector_type(4))) float f32x4;

__device__ inline unsigned short f2h(float f) {
  union { _Float16 h; unsigned short u; } c;
  c.h = (_Float16)f;
  return c.u;
}
__device__ inline float h2f(unsigned short u) {
  union { _Float16 h; unsigned short u; } c;
  c.u = u;
  return (float)c.h;
}

// ---------------- transpose + f32->f16 convert: dst[n][k] = src[k][n] ----------------
// grid: (N/32, K/32, E), block 256
__launch_bounds__(256)
__global__ void tcvt_k(const float* __restrict__ src, unsigned short* __restrict__ dst,
                       int K, int N) {
  int e = blockIdx.z;
  src += (size_t)e * K * N;
  dst += (size_t)e * K * N;
  int n0 = blockIdx.x * 32, k0 = blockIdx.y * 32;
  __shared__ float ts[32][33];
  int tid = threadIdx.x;
  int r = tid >> 3, c4 = (tid & 7) * 4;
  float4 v = *(const float4*)(src + (size_t)(k0 + r) * N + n0 + c4);
  ts[r][c4] = v.x; ts[r][c4 + 1] = v.y; ts[r][c4 + 2] = v.z; ts[r][c4 + 3] = v.w;
  __syncthreads();
  ushort4 o;
  o.x = f2h(ts[c4][r]);
  o.y = f2h(ts[c4 + 1][r]);
  o.z = f2h(ts[c4 + 2][r]);
  o.w = f2h(ts[c4 + 3][r]);
  *(ushort4*)(dst + (size_t)(n0 + r) * K + k0 + c4) = o;
}

__launch_bounds__(64)
__global__ void zero_counters_k(int* __restrict__ counts, int* __restrict__ fill) {
  int i = threadIdx.x;
  if (i < N_EXP) { counts[i] = 0; fill[i] = 0; }
}

// rmsnorm: f32 in -> f16 out (+ optional f32 out2)
__launch_bounds__(256)
__global__ void rmsnorm_k(const float* __restrict__ x, int in_stride, int width,
                          const float* __restrict__ w, unsigned short* __restrict__ out,
                          float* __restrict__ out2, int out_stride) {
  int row = blockIdx.x;
  const float* xr = x + (size_t)row * in_stride;
  float ss = 0.f;
  for (int i = threadIdx.x; i < width; i += 256) { float v = xr[i]; ss += v * v; }
  #pragma unroll
  for (int off = 32; off; off >>= 1) ss += __shfl_down(ss, off, 64);
  __shared__ float red[4];
  if ((threadIdx.x & 63) == 0) red[threadIdx.x >> 6] = ss;
  __syncthreads();
  if (threadIdx.x == 0) {
    float tot = red[0] + red[1] + red[2] + red[3];
    red[0] = rsqrtf(tot / (float)width + 1e-6f);
  }
  __syncthreads();
  float scale = red[0];
  for (int i = threadIdx.x; i < width; i += 256) {
    float v = xr[i] * scale * w[i];
    out[(size_t)row * out_stride + i] = f2h(v);
    if (out2) out2[(size_t)row * out_stride + i] = v;
  }
}

// ---------------- MFMA f16 TN GEMM: C[M][N] = A[M][K] @ B^T[N][K] (+R) ----------------
// grid: (N/64, M/64), block 256
template <int RES, int OUTH>
__launch_bounds__(256)
__global__ void gemm_bt_k(const unsigned short* __restrict__ A,
                          const unsigned short* __restrict__ B,
                          const float* __restrict__ R, void* __restrict__ Cout,
                          int N, int K) {
  const int n0 = blockIdx.x * 64;
  const int m0 = blockIdx.y * 64;
  __shared__ __align__(16) unsigned short As[64][72];
  __shared__ __align__(16) unsigned short Bs[64][72];
  const int tid = threadIdx.x;
  const int lane = tid & 63, wave = tid >> 6;
  const int quad = lane >> 4, lm = lane & 15;
  const int wm = (wave >> 1) * 32, wn = (wave & 1) * 32;
  f32x4 acc[2][2] = {};
  const int sr = tid >> 2, sc = tid & 3;
  const unsigned short* Ap = A + (size_t)(m0 + sr) * K;
  const unsigned short* Bp = B + (size_t)(n0 + sr) * K;
  for (int k0 = 0; k0 < K; k0 += 64) {
    f16x8 a0 = *(const f16x8*)(Ap + k0 + sc * 8);
    f16x8 a1 = *(const f16x8*)(Ap + k0 + sc * 8 + 32);
    f16x8 b0 = *(const f16x8*)(Bp + k0 + sc * 8);
    f16x8 b1 = *(const f16x8*)(Bp + k0 + sc * 8 + 32);
    __syncthreads();
    *(f16x8*)&As[sr][sc * 8] = a0;
    *(f16x8*)&As[sr][sc * 8 + 32] = a1;
    *(f16x8*)&Bs[sr][sc * 8] = b0;
    *(f16x8*)&Bs[sr][sc * 8 + 32] = b1;
    __syncthreads();
    #pragma unroll
    for (int ks = 0; ks < 2; ks++) {
      f16x8 af0 = *(const f16x8*)&As[wm + lm][ks * 32 + quad * 8];
      f16x8 af1 = *(const f16x8*)&As[wm + 16 + lm][ks * 32 + quad * 8];
      f16x8 bf0 = *(const f16x8*)&Bs[wn + lm][ks * 32 + quad * 8];
      f16x8 bf1 = *(const f16x8*)&Bs[wn + 16 + lm][ks * 32 + quad * 8];
      acc[0][0] = __builtin_amdgcn_mfma_f32_16x16x32_f16(af0, bf0, acc[0][0], 0, 0, 0);
      acc[0][1] = __builtin_amdgcn_mfma_f32_16x16x32_f16(af0, bf1, acc[0][1], 0, 0, 0);
      acc[1][0] = __builtin_amdgcn_mfma_f32_16x16x32_f16(af1, bf0, acc[1][0], 0, 0, 0);
      acc[1][1] = __builtin_amdgcn_mfma_f32_16x16x32_f16(af1, bf1, acc[1][1], 0, 0, 0);
    }
  }
  #pragma unroll
  for (int i = 0; i < 2; i++)
    #pragma unroll
    for (int j = 0; j < 2; j++) {
      int row = m0 + wm + i * 16 + quad * 4;
      int col = n0 + wn + j * 16 + lm;
      #pragma unroll
      for (int r = 0; r < 4; r++) {
        float v = acc[i][j][r];
        if (RES) v += R[(size_t)(row + r) * N + col];
        if (OUTH) ((unsigned short*)Cout)[(size_t)(row + r) * N + col] = f2h(v);
        else ((float*)Cout)[(size_t)(row + r) * N + col] = v;
      }
    }
}

// ---------------- MoE up: h = silu(A@w1^T)*(A@w3^T), gathered token rows ----------------
// grid: (INTER/64, mtiles, E)
__launch_bounds__(256)
__global__ void moe_up_k(const unsigned short* __restrict__ xfb,
                         const unsigned short* __restrict__ w1t,
                         const unsigned short* __restrict__ w3t,
                         unsigned short* __restrict__ hout,
                         const int* __restrict__ perm, const int* __restrict__ offs,
                         int Mfull) {
  const int e = blockIdx.z;
  int base = 0, count = Mfull;
  if (offs) { base = offs[e]; count = offs[e + 1] - base; }
  const int m0 = blockIdx.y * 64;
  if (m0 >= count) return;
  const int n0 = blockIdx.x * 64;
  const unsigned short* W1 = w1t + (size_t)e * (INTER * DIM);
  const unsigned short* W3 = w3t + (size_t)e * (INTER * DIM);
  __shared__ __align__(16) unsigned short As[64][72];
  __shared__ __align__(16) unsigned short B1s[64][72];
  __shared__ __align__(16) unsigned short B2s[64][72];
  __shared__ int toks[64];
  const int tid = threadIdx.x;
  if (tid < 64) {
    int g = m0 + tid;
    toks[tid] = (g < count) ? (perm ? (perm[base + g] >> 2) : g) : -1;
  }
  __syncthreads();
  const int lane = tid & 63, wave = tid >> 6;
  const int quad = lane >> 4, lm = lane & 15;
  const int wm = (wave >> 1) * 32, wn = (wave & 1) * 32;
  f32x4 acc1[2][2] = {};
  f32x4 acc2[2][2] = {};
  const int sr = tid >> 2, sc = tid & 3;
  const int tok = toks[sr];
  const unsigned short* Ap = xfb + (size_t)(tok < 0 ? 0 : tok) * DIM;
  const bool av = (tok >= 0);
  const unsigned short* B1p = W1 + (size_t)(n0 + sr) * DIM;
  const unsigned short* B2p = W3 + (size_t)(n0 + sr) * DIM;
  for (int k0 = 0; k0 < DIM; k0 += 64) {
    f16x8 a0 = {0,0,0,0,0,0,0,0}, a1 = {0,0,0,0,0,0,0,0};
    if (av) {
      a0 = *(const f16x8*)(Ap + k0 + sc * 8);
      a1 = *(const f16x8*)(Ap + k0 + sc * 8 + 32);
    }
    f16x8 b10 = *(const f16x8*)(B1p + k0 + sc * 8);
    f16x8 b11 = *(const f16x8*)(B1p + k0 + sc * 8 + 32);
    f16x8 b20 = *(const f16x8*)(B2p + k0 + sc * 8);
    f16x8 b21 = *(const f16x8*)(B2p + k0 + sc * 8 + 32);
    __syncthreads();
    *(f16x8*)&As[sr][sc * 8] = a0;
    *(f16x8*)&As[sr][sc * 8 + 32] = a1;
    *(f16x8*)&B1s[sr][sc * 8] = b10;
    *(f16x8*)&B1s[sr][sc * 8 + 32] = b11;
    *(f16x8*)&B2s[sr][sc * 8] = b20;
    *(f16x8*)&B2s[sr][sc * 8 + 32] = b21;
    __syncthreads();
    #pragma unroll
    for (int ks = 0; ks < 2; ks++) {
      f16x8 af0 = *(const f16x8*)&As[wm + lm][ks * 32 + quad * 8];
      f16x8 af1 = *(const f16x8*)&As[wm + 16 + lm][ks * 32 + quad * 8];
      f16x8 b1f0 = *(const f16x8*)&B1s[wn + lm][ks * 32 + quad * 8];
      f16x8 b1f1 = *(const f16x8*)&B1s[wn + 16 + lm][ks * 32 + quad * 8];
      f16x8 b2f0 = *(const f16x8*)&B2s[wn + lm][ks * 32 + quad * 8];
      f16x8 b2f1 = *(const f16x8*)&B2s[wn + 16 + lm][ks * 32 + quad * 8];
      acc1[0][0] = __builtin_amdgcn_mfma_f32_16x16x32_f16(af0, b1f0, acc1[0][0], 0, 0, 0);
      acc1[0][1] = __builtin_amdgcn_mfma_f32_16x16x32_f16(af0, b1f1, acc1[0][1], 0, 0, 0);
      acc1[1][0] = __builtin_amdgcn_mfma_f32_16x16x32_f16(af1, b1f0, acc1[1][0], 0, 0, 0);
      acc1[1][1] = __builtin_amdgcn_mfma_f32_16x16x32_f16(af1, b1f1, acc1[1][1], 0, 0, 0);
      acc2[0][0] = __builtin_amdgcn_mfma_f32_16x16x32_f16(af0, b2f0, acc2[0][0], 0, 0, 0);
      acc2[0][1] = __builtin_amdgcn_mfma_f32_16x16x32_f16(af0, b2f1, acc2[0][1], 0, 0, 0);
      acc2[1][0] = __builtin_amdgcn_mfma_f32_16x16x32_f16(af1, b2f0, acc2[1][0], 0, 0, 0);
      acc2[1][1] = __builtin_amdgcn_mfma_f32_16x16x32_f16(af1, b2f1, acc2[1][1], 0, 0, 0);
    }
  }
  #pragma unroll
  for (int i = 0; i < 2; i++)
    #pragma unroll
    for (int j = 0; j < 2; j++) {
      int col = n0 + wn + j * 16 + lm;
      #pragma unroll
      for (int r = 0; r < 4; r++) {
        int g = m0 + wm + i * 16 + quad * 4 + r;
        if (g < count) {
          float u = acc1[i][j][r];
          float vv = acc2[i][j][r];
          float h = (u / (1.f + __expf(-u))) * vv;
          hout[(size_t)(base + g) * INTER + col] = f2h(h);
        }
      }
    }
}

// ---------------- MoE down: dout rows (permuted order) = h @ w2^T ----------------
// grid: (DIM/64, mtiles, E)
__launch_bounds__(256)
__global__ void moe_down_k(const unsigned short* __restrict__ hbuf,
                           const unsigned short* __restrict__ w2t,
                           unsigned short* __restrict__ dout,
                           const int* __restrict__ offs, int Mfull) {
  const int e = blockIdx.z;
  int base = 0, count = Mfull;
  if (offs) { base = offs[e]; count = offs[e + 1] - base; }
  const int m0 = blockIdx.y * 64;
  if (m0 >= count) return;
  const int n0 = blockIdx.x * 64;
  const unsigned short* W2 = w2t + (size_t)e * (DIM * INTER);
  __shared__ __align__(16) unsigned short As[64][72];
  __shared__ __align__(16) unsigned short Bs[64][72];
  const int tid = threadIdx.x;
  const int lane = tid & 63, wave = tid >> 6;
  const int quad = lane >> 4, lm = lane & 15;
  const int wm = (wave >> 1) * 32, wn = (wave & 1) * 32;
  f32x4 acc[2][2] = {};
  const int sr = tid >> 2, sc = tid & 3;
  const int g_s = m0 + sr;
  const bool av = (g_s < count);
  const unsigned short* Ap = hbuf + (size_t)(base + (av ? g_s : 0)) * INTER;
  const unsigned short* Bp = W2 + (size_t)(n0 + sr) * INTER;
  for (int k0 = 0; k0 < INTER; k0 += 64) {
    f16x8 a0 = {0,0,0,0,0,0,0,0}, a1 = {0,0,0,0,0,0,0,0};
    if (av) {
      a0 = *(const f16x8*)(Ap + k0 + sc * 8);
      a1 = *(const f16x8*)(Ap + k0 + sc * 8 + 32);
    }
    f16x8 b0 = *(const f16x8*)(Bp + k0 + sc * 8);
    f16x8 b1 = *(const f16x8*)(Bp + k0 + sc * 8 + 32);
    __syncthreads();
    *(f16x8*)&As[sr][sc * 8] = a0;
    *(f16x8*)&As[sr][sc * 8 + 32] = a1;
    *(f16x8*)&Bs[sr][sc * 8] = b0;
    *(f16x8*)&Bs[sr][sc * 8 + 32] = b1;
    __syncthreads();
    #pragma unroll
    for (int ks = 0; ks < 2; ks++) {
      f16x8 af0 = *(const f16x8*)&As[wm + lm][ks * 32 + quad * 8];
      f16x8 af1 = *(const f16x8*)&As[wm + 16 + lm][ks * 32 + quad * 8];
      f16x8 bf0 = *(const f16x8*)&Bs[wn + lm][ks * 32 + quad * 8];
      f16x8 bf1 = *(const f16x8*)&Bs[wn + 16 + lm][ks * 32 + quad * 8];
      acc[0][0] = __builtin_amdgcn_mfma_f32_16x16x32_f16(af0, bf0, acc[0][0], 0, 0, 0);
      acc[0][1] = __builtin_amdgcn_mfma_f32_16x16x32_f16(af0, bf1, acc[0][1], 0, 0, 0);
      acc[1][0] = __builtin_amdgcn_mfma_f32_16x16x32_f16(af1, bf0, acc[1][0], 0, 0, 0);
      acc[1][1] = __builtin_amdgcn_mfma_f32_16x16x32_f16(af1, bf1, acc[1][1], 0, 0, 0);
    }
  }
  #pragma unroll
  for (int i = 0; i < 2; i++)
    #pragma unroll
    for (int j = 0; j < 2; j++) {
      int col = n0 + wn + j * 16 + lm;
      #pragma unroll
      for (int r = 0; r < 4; r++) {
        int g = m0 + wm + i * 16 + quad * 4 + r;
        if (g < count)
          dout[(size_t)(base + g) * DIM + col] = f2h(acc[i][j][r]);
      }
    }
}

// ---------------- attention: MFMA f16 flash, 64-query tiles ----------------
// grid: (S/64, HEADS, B), block 256 (4 waves; wave owns 16 query rows)
__launch_bounds__(256)
__global__ void attn_k(const unsigned short* __restrict__ q,
                       const unsigned short* __restrict__ kvp,
                       const float* __restrict__ kvb,
                       unsigned short* __restrict__ o) {
  const int qt = blockIdx.x, h = blockIdx.y, b = blockIdx.z;
  __shared__ __align__(16) _Float16 Qs[64][136];
  __shared__ __align__(16) _Float16 Ks[64][136];
  __shared__ __align__(16) _Float16 Vt[128][72];
  __shared__ __align__(16) _Float16 Ps[4][16][72];
  const int tid = threadIdx.x;
  const int lane = tid & 63, wave = tid >> 6;
  const int quad = lane >> 4, lm = lane & 15;
  const int qr0 = wave * 16;
  const float scale = 0.08838834764831845f;  // 128^-0.5
  const int tq = b * S_LEN + qt * 64;

  // stage Q (64 x 128): per wave iter, fixed g, key=lane -> 2-way free
  for (int i = tid; i < 64 * 16; i += 256) {
    int row = i & 63, g = i >> 6;
    *(f16x8*)&Qs[row][g * 8] =
        *(const f16x8*)(q + (size_t)(tq + row) * 1024 + h * 128 + g * 8);
  }

  float m_i[4], l_i[4];
  #pragma unroll
  for (int r = 0; r < 4; r++) { m_i[r] = -1e30f; l_i[r] = 0.f; }
  f32x4 o_acc[8] = {};

  for (int kt = 0; kt <= qt; ++kt) {
    const int tk = b * S_LEN + kt * 64;
    // K nope (f16 from kvp)
    for (int i = tid; i < 64 * 8; i += 256) {
      int key = i & 63, g = i >> 6;
      *(f16x8*)&Ks[key][g * 8] =
          *(const f16x8*)(kvp + (size_t)(tk + key) * KVP_W + h * 192 + g * 8);
    }
    // K rope (f32 from kvb, shared across heads)
    for (int i = tid; i < 64 * 16; i += 256) {
      int key = i & 63, g = i >> 6;
      float4 v = *(const float4*)(kvb + (size_t)(tk + key) * 320 + 256 + g * 4);
      ushort4 u;
      u.x = f2h(v.x); u.y = f2h(v.y); u.z = f2h(v.z); u.w = f2h(v.w);
      *(ushort4*)&Ks[key][64 + g * 4] = u;
    }
    // V transposed: Vt[d][key]
    for (int i = tid; i < 64 * 16; i += 256) {
      int key = i & 63, g = i >> 6;
      f16x8 v = *(const f16x8*)(kvp + (size_t)(tk + key) * KVP_W + h * 192 + 64 + g * 8);
      #pragma unroll
      for (int j = 0; j < 8; j++) Vt[g * 8 + j][key] = v[j];
    }
    __syncthreads();

    // QK^T: 16x64 S-tile per wave
    f32x4 sacc[4] = {};
    #pragma unroll
    for (int kc = 0; kc < 4; kc++) {
      f16x8 af = *(const f16x8*)&Qs[qr0 + lm][kc * 32 + quad * 8];
      #pragma unroll
      for (int jn = 0; jn < 4; jn++) {
        f16x8 bf = *(const f16x8*)&Ks[jn * 16 + lm][kc * 32 + quad * 8];
        sacc[jn] = __builtin_amdgcn_mfma_f32_16x16x32_f16(af, bf, sacc[jn], 0, 0, 0);
      }
    }
    const bool diag = (kt == qt);
    float p[4][4];  // [jn][r]
    float rowmax[4], rowsum[4];
    #pragma unroll
    for (int r = 0; r < 4; r++) rowmax[r] = -1e30f;
    #pragma unroll
    for (int jn = 0; jn < 4; jn++)
      #pragma unroll
      for (int r = 0; r < 4; r++) {
        float s = sacc[jn][r] * scale;
        if (diag && (jn * 16 + lm > qr0 + quad * 4 + r)) s = -1e30f;
        p[jn][r] = s;
        rowmax[r] = fmaxf(rowmax[r], s);
      }
    #pragma unroll
    for (int m = 1; m < 16; m <<= 1)
      #pragma unroll
      for (int r = 0; r < 4; r++)
        rowmax[r] = fmaxf(rowmax[r], __shfl_xor(rowmax[r], m, 64));
    float al[4];
    #pragma unroll
    for (int r = 0; r < 4; r++) {
      float mn = fmaxf(m_i[r], rowmax[r]);
      al[r] = __expf(m_i[r] - mn);
      m_i[r] = mn;
      rowsum[r] = 0.f;
    }
    #pragma unroll
    for (int jn = 0; jn < 4; jn++)
      #pragma unroll
      for (int r = 0; r < 4; r++) {
        float pv = __expf(p[jn][r] - m_i[r]);
        p[jn][r] = pv;
        rowsum[r] += pv;
      }
    #pragma unroll
    for (int m = 1; m < 16; m <<= 1)
      #pragma unroll
      for (int r = 0; r < 4; r++)
        rowsum[r] += __shfl_xor(rowsum[r], m, 64);
    #pragma unroll
    for (int r = 0; r < 4; r++) l_i[r] = l_i[r] * al[r] + rowsum[r];
    #pragma unroll
    for (int jn2 = 0; jn2 < 8; jn2++)
      #pragma unroll
      for (int r = 0; r < 4; r++) o_acc[jn2][r] *= al[r];
    // P: C-layout regs -> wave-local LDS (A-layout readable)
    #pragma unroll
    for (int jn = 0; jn < 4; jn++)
      #pragma unroll
      for (int r = 0; r < 4; r++)
        Ps[wave][quad * 4 + r][jn * 16 + lm] = (_Float16)p[jn][r];
    // PV: O-tile 16x128 per wave
    #pragma unroll
    for (int kc = 0; kc < 2; kc++) {
      f16x8 af = *(const f16x8*)&Ps[wave][lm][kc * 32 + quad * 8];
      #pragma unroll
      for (int jn2 = 0; jn2 < 8; jn2++) {
        f16x8 bf = *(const f16x8*)&Vt[jn2 * 16 + lm][kc * 32 + quad * 8];
        o_acc[jn2] = __builtin_amdgcn_mfma_f32_16x16x32_f16(af, bf, o_acc[jn2], 0, 0, 0);
      }
    }
    __syncthreads();
  }
  #pragma unroll
  for (int r = 0; r < 4; r++) l_i[r] = 1.f / l_i[r];
  #pragma unroll
  for (int jn2 = 0; jn2 < 8; jn2++) {
    int col = h * 128 + jn2 * 16 + lm;
    #pragma unroll
    for (int r = 0; r < 4; r++) {
      int row = tq + qr0 + quad * 4 + r;
      o[(size_t)row * 1024 + col] = f2h(o_acc[jn2][r] * l_i[r]);
    }
  }
}

// ---------------- gate / routing ----------------
__launch_bounds__(256)
__global__ void gate_k(const float* __restrict__ xf, const float* __restrict__ gw,
                       const float* __restrict__ gb, float* __restrict__ tw,
                       int* __restrict__ tidx, int* __restrict__ counts) {
  int t = blockIdx.x;
  __shared__ float xs[DIM];
  __shared__ float part[256];
  __shared__ float sc[N_EXP];
  int tid = threadIdx.x;
  for (int i = tid; i < DIM; i += 256) xs[i] = xf[(size_t)t * DIM + i];
  __syncthreads();
  {
    int e = tid >> 3, p = tid & 7;
    float s = 0.f;
    const float* ge = gw + (size_t)e * DIM + p * 128;
    const float* xp = xs + p * 128;
    for (int d = 0; d < 128; d++) s += xp[d] * ge[d];
    part[tid] = s;
  }
  __syncthreads();
  if (tid < N_EXP) {
    float tot = 0.f;
    for (int p = 0; p < 8; p++) tot += part[tid * 8 + p];
    sc[tid] = 1.f / (1.f + __expf(-tot));
  }
  __syncthreads();
  if (tid == 0) {
    float orig[N_EXP], sb[N_EXP];
    for (int i = 0; i < N_EXP; i++) { orig[i] = sc[i]; sb[i] = orig[i] + gb[i]; }
    float gsc[8];
    for (int g = 0; g < 8; g++) {
      float m1 = -1e30f, m2 = -1e30f;
      for (int j = 0; j < 4; j++) {
        float v = sb[g * 4 + j];
        if (v > m1) { m2 = m1; m1 = v; } else if (v > m2) m2 = v;
      }
      gsc[g] = m1 + m2;
    }
    bool gok[8] = {false, false, false, false, false, false, false, false};
    for (int it = 0; it < 4; it++) {
      int best = 0; float bv = -1e30f;
      for (int g = 0; g < 8; g++)
        if (!gok[g] && gsc[g] >= bv) { bv = gsc[g]; best = g; }
      gok[best] = true;
    }
    bool taken[N_EXP] = {};
    int idx[TOPK]; float wsum = 0.f;
    for (int k = 0; k < TOPK; k++) {
      int best = 0; float bv = -1e30f;
      for (int i = 0; i < N_EXP; i++)
        if (gok[i >> 2] && !taken[i] && sb[i] >= bv) { bv = sb[i]; best = i; }
      taken[best] = true; idx[k] = best; wsum += orig[best];
    }
    float inv = 1.f / (wsum + 1e-20f);
    for (int k = 0; k < TOPK; k++) {
      tidx[t * TOPK + k] = idx[k];
      tw[t * TOPK + k] = orig[idx[k]] * inv;
      atomicAdd(&counts[idx[k]], 1);
    }
  }
}

__global__ void scan_k(const int* __restrict__ counts, int* __restrict__ offs) {
  if (threadIdx.x == 0 && blockIdx.x == 0) {
    int acc = 0;
    for (int e = 0; e < N_EXP; e++) { offs[e] = acc; acc += counts[e]; }
    offs[N_EXP] = acc;
  }
}

__launch_bounds__(256)
__global__ void scatter_k(const int* __restrict__ tidx, const int* __restrict__ offs,
                          int* __restrict__ fill, int* __restrict__ perm,
                          int* __restrict__ posOf) {
  int t = blockIdx.x * 256 + threadIdx.x;
  if (t >= T_TOK) return;
  for (int j = 0; j < TOPK; j++) {
    int e = tidx[t * TOPK + j];
    int pos = atomicAdd(&fill[e], 1);
    int p = offs[e] + pos;
    perm[p] = t * TOPK + j;
    posOf[t * TOPK + j] = p;
  }
}

// ---------------- final combine ----------------
__launch_bounds__(256)
__global__ void final_gather_k(const float* __restrict__ x1,
                               const unsigned short* __restrict__ dbuf,
                               const unsigned short* __restrict__ sdbuf,
                               const int* __restrict__ posOf,
                               const float* __restrict__ tw,
                               float* __restrict__ out) {
  int t = blockIdx.x;
  int c0 = threadIdx.x * 4;
  int p0 = posOf[t * 4 + 0], p1 = posOf[t * 4 + 1];
  int p2 = posOf[t * 4 + 2], p3 = posOf[t * 4 + 3];
  float w0 = tw[t * 4 + 0], w1 = tw[t * 4 + 1];
  float w2 = tw[t * 4 + 2], w3 = tw[t * 4 + 3];
  size_t tb = (size_t)t * DIM;
  #pragma unroll
  for (int i = 0; i < 4; i++) {
    int c = c0 + i;
    float v = x1[tb + c] + h2f(sdbuf[tb + c])
            + w0 * h2f(dbuf[(size_t)p0 * DIM + c])
            + w1 * h2f(dbuf[(size_t)p1 * DIM + c])
            + w2 * h2f(dbuf[(size_t)p2 * DIM + c])
            + w3 * h2f(dbuf[(size_t)p3 * DIM + c]);
    out[tb + c] = v;
  }
}

// ---------------- host launch ----------------
extern "C" void kernel_launch(void* const* d_in, const int* in_sizes, int n_in,
                              void* d_out, int out_size, void* d_ws, size_t ws_size,
                              hipStream_t stream) {
  const float* x        = (const float*)d_in[0];
  const float* norm_attn= (const float*)d_in[1];
  const float* wq       = (const float*)d_in[2];
  const float* wkv_a    = (const float*)d_in[3];
  const float* kv_norm_w= (const float*)d_in[4];
  const float* wkv_b    = (const float*)d_in[5];
  const float* wo       = (const float*)d_in[6];
  const float* norm_moe = (const float*)d_in[7];
  const float* gate_w   = (const float*)d_in[8];
  const float* gate_b   = (const float*)d_in[9];
  const float* ew1      = (const float*)d_in[10];
  const float* ew2      = (const float*)d_in[11];
  const float* ew3      = (const float*)d_in[12];
  const float* sw1      = (const float*)d_in[13];
  const float* sw2      = (const float*)d_in[14];
  const float* sw3      = (const float*)d_in[15];
  float* out = (float*)d_out;

  char* wp = (char*)d_ws;
  auto alloc = [&](size_t bytes) -> char* {
    char* r = wp;
    wp += (bytes + 255) & ~(size_t)255;
    return r;
  };
  typedef unsigned short us;
  us* wqT   = (us*)alloc(1048576 * 2);
  us* wkvaT = (us*)alloc(327680 * 2);
  us* wkvbT = (us*)alloc(393216 * 2);
  us* woT   = (us*)alloc(1048576 * 2);
  us* ew1T  = (us*)alloc((size_t)16777216 * 2);
  us* ew3T  = (us*)alloc((size_t)16777216 * 2);
  us* ew2T  = (us*)alloc((size_t)16777216 * 2);
  us* sw1T  = (us*)alloc(524288 * 2);
  us* sw3T  = (us*)alloc(524288 * 2);
  us* sw2T  = (us*)alloc(524288 * 2);
  us* xb    = (us*)alloc(2097152 * 2);   // xn, later xfb
  us* cn    = (us*)alloc(524288 * 2);
  us* atn   = (us*)alloc(2097152 * 2);
  us* dbuf  = (us*)alloc((size_t)8388608 * 2);
  us* qb    = (us*)alloc(2097152 * 4);    // f16 q; later sdbuf aliases
  float* kvb  = (float*)alloc(655360 * 4);
  us* kvp   = (us*)alloc(3145728 * 4);    // f16 kvp; later hbuf+hs alias
  float* x1   = (float*)alloc(2097152 * 4);
  float* xf32 = (float*)alloc(2097152 * 4);
  float* twb  = (float*)alloc(8192 * 4);
  int* tidx   = (int*)alloc(8192 * 4);
  int* perm   = (int*)alloc(8192 * 4);
  int* posOf  = (int*)alloc(8192 * 4);
  int* counts = (int*)alloc(64 * 4);
  int* offs   = (int*)alloc(64 * 4);
  int* fill   = (int*)alloc(64 * 4);
  us* sdbuf = qb;
  us* hbuf  = kvp;
  us* hs    = hbuf + (size_t)8192 * 512;

  // weight transpose + convert
  tcvt_k<<<dim3(32, 32, 1), 256, 0, stream>>>(wq, wqT, 1024, 1024);
  tcvt_k<<<dim3(10, 32, 1), 256, 0, stream>>>(wkv_a, wkvaT, 1024, 320);
  tcvt_k<<<dim3(48, 8, 1), 256, 0, stream>>>(wkv_b, wkvbT, 256, 1536);
  tcvt_k<<<dim3(32, 32, 1), 256, 0, stream>>>(wo, woT, 1024, 1024);
  tcvt_k<<<dim3(16, 32, 32), 256, 0, stream>>>(ew1, ew1T, 1024, 512);
  tcvt_k<<<dim3(16, 32, 32), 256, 0, stream>>>(ew3, ew3T, 1024, 512);
  tcvt_k<<<dim3(32, 16, 32), 256, 0, stream>>>(ew2, ew2T, 512, 1024);
  tcvt_k<<<dim3(16, 32, 1), 256, 0, stream>>>(sw1, sw1T, 1024, 512);
  tcvt_k<<<dim3(16, 32, 1), 256, 0, stream>>>(sw3, sw3T, 1024, 512);
  tcvt_k<<<dim3(32, 16, 1), 256, 0, stream>>>(sw2, sw2T, 512, 1024);

  // ---- MLA ----
  rmsnorm_k<<<T_TOK, 256, 0, stream>>>(x, DIM, DIM, norm_attn, xb, nullptr, DIM);
  gemm_bt_k<0, 1><<<dim3(16, 32), 256, 0, stream>>>(xb, wqT, nullptr, qb, 1024, 1024);
  gemm_bt_k<0, 0><<<dim3(5, 32), 256, 0, stream>>>(xb, wkvaT, nullptr, kvb, 320, 1024);
  rmsnorm_k<<<T_TOK, 256, 0, stream>>>(kvb, 320, KV_LORA, kv_norm_w, cn, nullptr, KV_LORA);
  gemm_bt_k<0, 1><<<dim3(24, 32), 256, 0, stream>>>(cn, wkvbT, nullptr, kvp, 1536, 256);
  attn_k<<<dim3(S_LEN / 64, HEADS, 2), 256, 0, stream>>>(qb, kvp, kvb, atn);
  gemm_bt_k<1, 0><<<dim3(16, 32), 256, 0, stream>>>(atn, woT, x, x1, 1024, 1024);

  // ---- MoE ----
  rmsnorm_k<<<T_TOK, 256, 0, stream>>>(x1, DIM, DIM, norm_moe, xb, xf32, DIM);
  zero_counters_k<<<1, 64, 0, stream>>>(counts, fill);
  gate_k<<<T_TOK, 256, 0, stream>>>(xf32, gate_w, gate_b, twb, tidx, counts);
  scan_k<<<1, 1, 0, stream>>>(counts, offs);
  scatter_k<<<(T_TOK + 255) / 256, 256, 0, stream>>>(tidx, offs, fill, perm, posOf);
  moe_up_k<<<dim3(8, 32, 32), 256, 0, stream>>>(xb, ew1T, ew3T, hbuf, perm, offs, 0);
  moe_down_k<<<dim3(16, 32, 32), 256, 0, stream>>>(hbuf, ew2T, dbuf, offs, 0);
  moe_up_k<<<dim3(8, 32, 1), 256, 0, stream>>>(xb, sw1T, sw3T, hs, nullptr, nullptr, T_TOK);
  moe_down_k<<<dim3(16, 32, 1), 256, 0, stream>>>(hs, sw2T, sdbuf, nullptr, T_TOK);

  final_gather_k<<<T_TOK, 256, 0, stream>>>(x1, dbuf, sdbuf, posOf, twb, out);
}

// Round 5
// 583.201 us; speedup vs baseline: 5.9942x; 1.0299x over previous
//
#include <hip/hip_runtime.h>
#include <hip/hip_bf16.h>

#define T_TOK 2048
#define DIM 1024
#define HEADS 8
#define QK_HD 128
#define V_HD 128
#define NOPE 64
#define ROPE 64
#define KV_LORA 256
#define N_EXP 32
#define TOPK 4
#define INTER 512
#define S_LEN 1024
#define KVP_W (HEADS * (NOPE + V_HD))   // 1536

typedef __attribute__((ext_vector_type(8))) _Float16 f16x8;
typedef __attribute__((ext_vector_type(4))) float f32x4;

__device__ inline unsigned short f2h(float f) {
  union { _Float16 h; unsigned short u; } c;
  c.h = (_Float16)f;
  return c.u;
}
__device__ inline float h2f(unsigned short u) {
  union { _Float16 h; unsigned short u; } c;
  c.u = u;
  return (float)c.h;
}

// ---------------- transpose + f32->f16 convert: dst[n][k] = src[k][n] ----------------
// grid: (N/32, K/32, E), block 256
__launch_bounds__(256)
__global__ void tcvt_k(const float* __restrict__ src, unsigned short* __restrict__ dst,
                       int K, int N) {
  int e = blockIdx.z;
  src += (size_t)e * K * N;
  dst += (size_t)e * K * N;
  int n0 = blockIdx.x * 32, k0 = blockIdx.y * 32;
  __shared__ float ts[32][33];
  int tid = threadIdx.x;
  int r = tid >> 3, c4 = (tid & 7) * 4;
  float4 v = *(const float4*)(src + (size_t)(k0 + r) * N + n0 + c4);
  ts[r][c4] = v.x; ts[r][c4 + 1] = v.y; ts[r][c4 + 2] = v.z; ts[r][c4 + 3] = v.w;
  __syncthreads();
  ushort4 o;
  o.x = f2h(ts[c4][r]);
  o.y = f2h(ts[c4 + 1][r]);
  o.z = f2h(ts[c4 + 2][r]);
  o.w = f2h(ts[c4 + 3][r]);
  *(ushort4*)(dst + (size_t)(n0 + r) * K + k0 + c4) = o;
}

__launch_bounds__(64)
__global__ void zero_counters_k(int* __restrict__ counts, int* __restrict__ fill) {
  int i = threadIdx.x;
  if (i < N_EXP) { counts[i] = 0; fill[i] = 0; }
}

// rmsnorm: f32 in -> f16 out (+ optional f32 out2)
__launch_bounds__(256)
__global__ void rmsnorm_k(const float* __restrict__ x, int in_stride, int width,
                          const float* __restrict__ w, unsigned short* __restrict__ out,
                          float* __restrict__ out2, int out_stride) {
  int row = blockIdx.x;
  const float* xr = x + (size_t)row * in_stride;
  float ss = 0.f;
  for (int i = threadIdx.x; i < width; i += 256) { float v = xr[i]; ss += v * v; }
  #pragma unroll
  for (int off = 32; off; off >>= 1) ss += __shfl_down(ss, off, 64);
  __shared__ float red[4];
  if ((threadIdx.x & 63) == 0) red[threadIdx.x >> 6] = ss;
  __syncthreads();
  if (threadIdx.x == 0) {
    float tot = red[0] + red[1] + red[2] + red[3];
    red[0] = rsqrtf(tot / (float)width + 1e-6f);
  }
  __syncthreads();
  float scale = red[0];
  for (int i = threadIdx.x; i < width; i += 256) {
    float v = xr[i] * scale * w[i];
    out[(size_t)row * out_stride + i] = f2h(v);
    if (out2) out2[(size_t)row * out_stride + i] = v;
  }
}

// ---------------- MFMA f16 TN GEMM: C[M][N] = A[M][K] @ B^T[N][K] (+R) ----------------
// grid: (N/64, M/64), block 256
template <int RES, int OUTH>
__launch_bounds__(256)
__global__ void gemm_bt_k(const unsigned short* __restrict__ A,
                          const unsigned short* __restrict__ B,
                          const float* __restrict__ R, void* __restrict__ Cout,
                          int N, int K) {
  const int n0 = blockIdx.x * 64;
  const int m0 = blockIdx.y * 64;
  __shared__ __align__(16) unsigned short As[64][72];
  __shared__ __align__(16) unsigned short Bs[64][72];
  const int tid = threadIdx.x;
  const int lane = tid & 63, wave = tid >> 6;
  const int quad = lane >> 4, lm = lane & 15;
  const int wm = (wave >> 1) * 32, wn = (wave & 1) * 32;
  f32x4 acc[2][2] = {};
  const int sr = tid >> 2, sc = tid & 3;
  const unsigned short* Ap = A + (size_t)(m0 + sr) * K;
  const unsigned short* Bp = B + (size_t)(n0 + sr) * K;
  for (int k0 = 0; k0 < K; k0 += 64) {
    f16x8 a0 = *(const f16x8*)(Ap + k0 + sc * 8);
    f16x8 a1 = *(const f16x8*)(Ap + k0 + sc * 8 + 32);
    f16x8 b0 = *(const f16x8*)(Bp + k0 + sc * 8);
    f16x8 b1 = *(const f16x8*)(Bp + k0 + sc * 8 + 32);
    __syncthreads();
    *(f16x8*)&As[sr][sc * 8] = a0;
    *(f16x8*)&As[sr][sc * 8 + 32] = a1;
    *(f16x8*)&Bs[sr][sc * 8] = b0;
    *(f16x8*)&Bs[sr][sc * 8 + 32] = b1;
    __syncthreads();
    #pragma unroll
    for (int ks = 0; ks < 2; ks++) {
      f16x8 af0 = *(const f16x8*)&As[wm + lm][ks * 32 + quad * 8];
      f16x8 af1 = *(const f16x8*)&As[wm + 16 + lm][ks * 32 + quad * 8];
      f16x8 bf0 = *(const f16x8*)&Bs[wn + lm][ks * 32 + quad * 8];
      f16x8 bf1 = *(const f16x8*)&Bs[wn + 16 + lm][ks * 32 + quad * 8];
      acc[0][0] = __builtin_amdgcn_mfma_f32_16x16x32_f16(af0, bf0, acc[0][0], 0, 0, 0);
      acc[0][1] = __builtin_amdgcn_mfma_f32_16x16x32_f16(af0, bf1, acc[0][1], 0, 0, 0);
      acc[1][0] = __builtin_amdgcn_mfma_f32_16x16x32_f16(af1, bf0, acc[1][0], 0, 0, 0);
      acc[1][1] = __builtin_amdgcn_mfma_f32_16x16x32_f16(af1, bf1, acc[1][1], 0, 0, 0);
    }
  }
  #pragma unroll
  for (int i = 0; i < 2; i++)
    #pragma unroll
    for (int j = 0; j < 2; j++) {
      int row = m0 + wm + i * 16 + quad * 4;
      int col = n0 + wn + j * 16 + lm;
      #pragma unroll
      for (int r = 0; r < 4; r++) {
        float v = acc[i][j][r];
        if (RES) v += R[(size_t)(row + r) * N + col];
        if (OUTH) ((unsigned short*)Cout)[(size_t)(row + r) * N + col] = f2h(v);
        else ((float*)Cout)[(size_t)(row + r) * N + col] = v;
      }
    }
}

// ---------------- MoE up: h = silu(A@w1^T)*(A@w3^T), gathered token rows ----------------
// grid: (INTER/64, mtiles, E)
__launch_bounds__(256)
__global__ void moe_up_k(const unsigned short* __restrict__ xfb,
                         const unsigned short* __restrict__ w1t,
                         const unsigned short* __restrict__ w3t,
                         unsigned short* __restrict__ hout,
                         const int* __restrict__ perm, const int* __restrict__ offs,
                         int Mfull) {
  const int e = blockIdx.z;
  int base = 0, count = Mfull;
  if (offs) { base = offs[e]; count = offs[e + 1] - base; }
  const int m0 = blockIdx.y * 64;
  if (m0 >= count) return;
  const int n0 = blockIdx.x * 64;
  const unsigned short* W1 = w1t + (size_t)e * (INTER * DIM);
  const unsigned short* W3 = w3t + (size_t)e * (INTER * DIM);
  __shared__ __align__(16) unsigned short As[64][72];
  __shared__ __align__(16) unsigned short B1s[64][72];
  __shared__ __align__(16) unsigned short B2s[64][72];
  __shared__ int toks[64];
  const int tid = threadIdx.x;
  if (tid < 64) {
    int g = m0 + tid;
    toks[tid] = (g < count) ? (perm ? (perm[base + g] >> 2) : g) : -1;
  }
  __syncthreads();
  const int lane = tid & 63, wave = tid >> 6;
  const int quad = lane >> 4, lm = lane & 15;
  const int wm = (wave >> 1) * 32, wn = (wave & 1) * 32;
  f32x4 acc1[2][2] = {};
  f32x4 acc2[2][2] = {};
  const int sr = tid >> 2, sc = tid & 3;
  const int tok = toks[sr];
  const unsigned short* Ap = xfb + (size_t)(tok < 0 ? 0 : tok) * DIM;
  const bool av = (tok >= 0);
  const unsigned short* B1p = W1 + (size_t)(n0 + sr) * DIM;
  const unsigned short* B2p = W3 + (size_t)(n0 + sr) * DIM;
  for (int k0 = 0; k0 < DIM; k0 += 64) {
    f16x8 a0 = {0,0,0,0,0,0,0,0}, a1 = {0,0,0,0,0,0,0,0};
    if (av) {
      a0 = *(const f16x8*)(Ap + k0 + sc * 8);
      a1 = *(const f16x8*)(Ap + k0 + sc * 8 + 32);
    }
    f16x8 b10 = *(const f16x8*)(B1p + k0 + sc * 8);
    f16x8 b11 = *(const f16x8*)(B1p + k0 + sc * 8 + 32);
    f16x8 b20 = *(const f16x8*)(B2p + k0 + sc * 8);
    f16x8 b21 = *(const f16x8*)(B2p + k0 + sc * 8 + 32);
    __syncthreads();
    *(f16x8*)&As[sr][sc * 8] = a0;
    *(f16x8*)&As[sr][sc * 8 + 32] = a1;
    *(f16x8*)&B1s[sr][sc * 8] = b10;
    *(f16x8*)&B1s[sr][sc * 8 + 32] = b11;
    *(f16x8*)&B2s[sr][sc * 8] = b20;
    *(f16x8*)&B2s[sr][sc * 8 + 32] = b21;
    __syncthreads();
    #pragma unroll
    for (int ks = 0; ks < 2; ks++) {
      f16x8 af0 = *(const f16x8*)&As[wm + lm][ks * 32 + quad * 8];
      f16x8 af1 = *(const f16x8*)&As[wm + 16 + lm][ks * 32 + quad * 8];
      f16x8 b1f0 = *(const f16x8*)&B1s[wn + lm][ks * 32 + quad * 8];
      f16x8 b1f1 = *(const f16x8*)&B1s[wn + 16 + lm][ks * 32 + quad * 8];
      f16x8 b2f0 = *(const f16x8*)&B2s[wn + lm][ks * 32 + quad * 8];
      f16x8 b2f1 = *(const f16x8*)&B2s[wn + 16 + lm][ks * 32 + quad * 8];
      acc1[0][0] = __builtin_amdgcn_mfma_f32_16x16x32_f16(af0, b1f0, acc1[0][0], 0, 0, 0);
      acc1[0][1] = __builtin_amdgcn_mfma_f32_16x16x32_f16(af0, b1f1, acc1[0][1], 0, 0, 0);
      acc1[1][0] = __builtin_amdgcn_mfma_f32_16x16x32_f16(af1, b1f0, acc1[1][0], 0, 0, 0);
      acc1[1][1] = __builtin_amdgcn_mfma_f32_16x16x32_f16(af1, b1f1, acc1[1][1], 0, 0, 0);
      acc2[0][0] = __builtin_amdgcn_mfma_f32_16x16x32_f16(af0, b2f0, acc2[0][0], 0, 0, 0);
      acc2[0][1] = __builtin_amdgcn_mfma_f32_16x16x32_f16(af0, b2f1, acc2[0][1], 0, 0, 0);
      acc2[1][0] = __builtin_amdgcn_mfma_f32_16x16x32_f16(af1, b2f0, acc2[1][0], 0, 0, 0);
      acc2[1][1] = __builtin_amdgcn_mfma_f32_16x16x32_f16(af1, b2f1, acc2[1][1], 0, 0, 0);
    }
  }
  #pragma unroll
  for (int i = 0; i < 2; i++)
    #pragma unroll
    for (int j = 0; j < 2; j++) {
      int col = n0 + wn + j * 16 + lm;
      #pragma unroll
      for (int r = 0; r < 4; r++) {
        int g = m0 + wm + i * 16 + quad * 4 + r;
        if (g < count) {
          float u = acc1[i][j][r];
          float vv = acc2[i][j][r];
          float h = (u / (1.f + __expf(-u))) * vv;
          hout[(size_t)(base + g) * INTER + col] = f2h(h);
        }
      }
    }
}

// ---------------- MoE down: dout rows (permuted order) = h @ w2^T ----------------
// grid: (DIM/64, mtiles, E)
__launch_bounds__(256)
__global__ void moe_down_k(const unsigned short* __restrict__ hbuf,
                           const unsigned short* __restrict__ w2t,
                           unsigned short* __restrict__ dout,
                           const int* __restrict__ offs, int Mfull) {
  const int e = blockIdx.z;
  int base = 0, count = Mfull;
  if (offs) { base = offs[e]; count = offs[e + 1] - base; }
  const int m0 = blockIdx.y * 64;
  if (m0 >= count) return;
  const int n0 = blockIdx.x * 64;
  const unsigned short* W2 = w2t + (size_t)e * (DIM * INTER);
  __shared__ __align__(16) unsigned short As[64][72];
  __shared__ __align__(16) unsigned short Bs[64][72];
  const int tid = threadIdx.x;
  const int lane = tid & 63, wave = tid >> 6;
  const int quad = lane >> 4, lm = lane & 15;
  const int wm = (wave >> 1) * 32, wn = (wave & 1) * 32;
  f32x4 acc[2][2] = {};
  const int sr = tid >> 2, sc = tid & 3;
  const int g_s = m0 + sr;
  const bool av = (g_s < count);
  const unsigned short* Ap = hbuf + (size_t)(base + (av ? g_s : 0)) * INTER;
  const unsigned short* Bp = W2 + (size_t)(n0 + sr) * INTER;
  for (int k0 = 0; k0 < INTER; k0 += 64) {
    f16x8 a0 = {0,0,0,0,0,0,0,0}, a1 = {0,0,0,0,0,0,0,0};
    if (av) {
      a0 = *(const f16x8*)(Ap + k0 + sc * 8);
      a1 = *(const f16x8*)(Ap + k0 + sc * 8 + 32);
    }
    f16x8 b0 = *(const f16x8*)(Bp + k0 + sc * 8);
    f16x8 b1 = *(const f16x8*)(Bp + k0 + sc * 8 + 32);
    __syncthreads();
    *(f16x8*)&As[sr][sc * 8] = a0;
    *(f16x8*)&As[sr][sc * 8 + 32] = a1;
    *(f16x8*)&Bs[sr][sc * 8] = b0;
    *(f16x8*)&Bs[sr][sc * 8 + 32] = b1;
    __syncthreads();
    #pragma unroll
    for (int ks = 0; ks < 2; ks++) {
      f16x8 af0 = *(const f16x8*)&As[wm + lm][ks * 32 + quad * 8];
      f16x8 af1 = *(const f16x8*)&As[wm + 16 + lm][ks * 32 + quad * 8];
      f16x8 bf0 = *(const f16x8*)&Bs[wn + lm][ks * 32 + quad * 8];
      f16x8 bf1 = *(const f16x8*)&Bs[wn + 16 + lm][ks * 32 + quad * 8];
      acc[0][0] = __builtin_amdgcn_mfma_f32_16x16x32_f16(af0, bf0, acc[0][0], 0, 0, 0);
      acc[0][1] = __builtin_amdgcn_mfma_f32_16x16x32_f16(af0, bf1, acc[0][1], 0, 0, 0);
      acc[1][0] = __builtin_amdgcn_mfma_f32_16x16x32_f16(af1, bf0, acc[1][0], 0, 0, 0);
      acc[1][1] = __builtin_amdgcn_mfma_f32_16x16x32_f16(af1, bf1, acc[1][1], 0, 0, 0);
    }
  }
  #pragma unroll
  for (int i = 0; i < 2; i++)
    #pragma unroll
    for (int j = 0; j < 2; j++) {
      int col = n0 + wn + j * 16 + lm;
      #pragma unroll
      for (int r = 0; r < 4; r++) {
        int g = m0 + wm + i * 16 + quad * 4 + r;
        if (g < count)
          dout[(size_t)(base + g) * DIM + col] = f2h(acc[i][j][r]);
      }
    }
}

// ---------------- attention: MFMA f16 flash, 64-query tiles ----------------
// grid: (S/64, HEADS, B), block 256 (4 waves; wave owns 16 query rows)
__launch_bounds__(256)
__global__ void attn_k(const unsigned short* __restrict__ q,
                       const unsigned short* __restrict__ kvp,
                       const float* __restrict__ kvb,
                       unsigned short* __restrict__ o) {
  const int qt = blockIdx.x, h = blockIdx.y, b = blockIdx.z;
  __shared__ __align__(16) _Float16 Qs[64][136];
  __shared__ __align__(16) _Float16 Ks[64][136];
  __shared__ __align__(16) _Float16 Vt[128][72];
  __shared__ __align__(16) _Float16 Ps[4][16][72];
  const int tid = threadIdx.x;
  const int lane = tid & 63, wave = tid >> 6;
  const int quad = lane >> 4, lm = lane & 15;
  const int qr0 = wave * 16;
  const float scale = 0.08838834764831845f;  // 128^-0.5
  const int tq = b * S_LEN + qt * 64;

  for (int i = tid; i < 64 * 16; i += 256) {
    int row = i & 63, g = i >> 6;
    *(f16x8*)&Qs[row][g * 8] =
        *(const f16x8*)(q + (size_t)(tq + row) * 1024 + h * 128 + g * 8);
  }

  float m_i[4], l_i[4];
  #pragma unroll
  for (int r = 0; r < 4; r++) { m_i[r] = -1e30f; l_i[r] = 0.f; }
  f32x4 o_acc[8] = {};

  for (int kt = 0; kt <= qt; ++kt) {
    const int tk = b * S_LEN + kt * 64;
    for (int i = tid; i < 64 * 8; i += 256) {
      int key = i & 63, g = i >> 6;
      *(f16x8*)&Ks[key][g * 8] =
          *(const f16x8*)(kvp + (size_t)(tk + key) * KVP_W + h * 192 + g * 8);
    }
    for (int i = tid; i < 64 * 16; i += 256) {
      int key = i & 63, g = i >> 6;
      float4 v = *(const float4*)(kvb + (size_t)(tk + key) * 320 + 256 + g * 4);
      ushort4 u;
      u.x = f2h(v.x); u.y = f2h(v.y); u.z = f2h(v.z); u.w = f2h(v.w);
      *(ushort4*)&Ks[key][64 + g * 4] = u;
    }
    for (int i = tid; i < 64 * 16; i += 256) {
      int key = i & 63, g = i >> 6;
      f16x8 v = *(const f16x8*)(kvp + (size_t)(tk + key) * KVP_W + h * 192 + 64 + g * 8);
      #pragma unroll
      for (int j = 0; j < 8; j++) Vt[g * 8 + j][key] = v[j];
    }
    __syncthreads();

    f32x4 sacc[4] = {};
    #pragma unroll
    for (int kc = 0; kc < 4; kc++) {
      f16x8 af = *(const f16x8*)&Qs[qr0 + lm][kc * 32 + quad * 8];
      #pragma unroll
      for (int jn = 0; jn < 4; jn++) {
        f16x8 bf = *(const f16x8*)&Ks[jn * 16 + lm][kc * 32 + quad * 8];
        sacc[jn] = __builtin_amdgcn_mfma_f32_16x16x32_f16(af, bf, sacc[jn], 0, 0, 0);
      }
    }
    const bool diag = (kt == qt);
    float p[4][4];
    float rowmax[4], rowsum[4];
    #pragma unroll
    for (int r = 0; r < 4; r++) rowmax[r] = -1e30f;
    #pragma unroll
    for (int jn = 0; jn < 4; jn++)
      #pragma unroll
      for (int r = 0; r < 4; r++) {
        float s = sacc[jn][r] * scale;
        if (diag && (jn * 16 + lm > qr0 + quad * 4 + r)) s = -1e30f;
        p[jn][r] = s;
        rowmax[r] = fmaxf(rowmax[r], s);
      }
    #pragma unroll
    for (int m = 1; m < 16; m <<= 1)
      #pragma unroll
      for (int r = 0; r < 4; r++)
        rowmax[r] = fmaxf(rowmax[r], __shfl_xor(rowmax[r], m, 64));
    float al[4];
    #pragma unroll
    for (int r = 0; r < 4; r++) {
      float mn = fmaxf(m_i[r], rowmax[r]);
      al[r] = __expf(m_i[r] - mn);
      m_i[r] = mn;
      rowsum[r] = 0.f;
    }
    #pragma unroll
    for (int jn = 0; jn < 4; jn++)
      #pragma unroll
      for (int r = 0; r < 4; r++) {
        float pv = __expf(p[jn][r] - m_i[r]);
        p[jn][r] = pv;
        rowsum[r] += pv;
      }
    #pragma unroll
    for (int m = 1; m < 16; m <<= 1)
      #pragma unroll
      for (int r = 0; r < 4; r++)
        rowsum[r] += __shfl_xor(rowsum[r], m, 64);
    #pragma unroll
    for (int r = 0; r < 4; r++) l_i[r] = l_i[r] * al[r] + rowsum[r];
    #pragma unroll
    for (int jn2 = 0; jn2 < 8; jn2++)
      #pragma unroll
      for (int r = 0; r < 4; r++) o_acc[jn2][r] *= al[r];
    #pragma unroll
    for (int jn = 0; jn < 4; jn++)
      #pragma unroll
      for (int r = 0; r < 4; r++)
        Ps[wave][quad * 4 + r][jn * 16 + lm] = (_Float16)p[jn][r];
    #pragma unroll
    for (int kc = 0; kc < 2; kc++) {
      f16x8 af = *(const f16x8*)&Ps[wave][lm][kc * 32 + quad * 8];
      #pragma unroll
      for (int jn2 = 0; jn2 < 8; jn2++) {
        f16x8 bf = *(const f16x8*)&Vt[jn2 * 16 + lm][kc * 32 + quad * 8];
        o_acc[jn2] = __builtin_amdgcn_mfma_f32_16x16x32_f16(af, bf, o_acc[jn2], 0, 0, 0);
      }
    }
    __syncthreads();
  }
  #pragma unroll
  for (int r = 0; r < 4; r++) l_i[r] = 1.f / l_i[r];
  #pragma unroll
  for (int jn2 = 0; jn2 < 8; jn2++) {
    int col = h * 128 + jn2 * 16 + lm;
    #pragma unroll
    for (int r = 0; r < 4; r++) {
      int row = tq + qr0 + quad * 4 + r;
      o[(size_t)row * 1024 + col] = f2h(o_acc[jn2][r] * l_i[r]);
    }
  }
}

// ---------------- gate scores: logits[T][32] = xf32 @ gw^T, f32 ----------------
// grid: T/32 blocks, 256 threads
__launch_bounds__(256)
__global__ void scores_k(const float* __restrict__ xf, const float* __restrict__ gw,
                         float* __restrict__ sc) {
  __shared__ float xls[32][129];
  __shared__ float gls[32][129];
  const int t0 = blockIdx.x * 32;
  const int tid = threadIdx.x;
  const int lr = tid >> 3, lc = tid & 7;   // loader: row, col-group
  const int e = tid & 31, tg = tid >> 5;   // compute: expert, token-group
  float acc[4] = {};
  for (int k0 = 0; k0 < DIM; k0 += 128) {
    __syncthreads();
    #pragma unroll
    for (int it = 0; it < 4; it++) {
      int col = lc * 4 + it * 32;
      *(float4*)&xls[lr][col] = *(const float4*)(xf + (size_t)(t0 + lr) * DIM + k0 + col);
      *(float4*)&gls[lr][col] = *(const float4*)(gw + (size_t)lr * DIM + k0 + col);
    }
    __syncthreads();
    for (int d = 0; d < 128; d++) {
      float g = gls[e][d];
      #pragma unroll
      for (int j = 0; j < 4; j++)
        acc[j] += xls[tg * 4 + j][d] * g;
    }
  }
  #pragma unroll
  for (int j = 0; j < 4; j++)
    sc[(size_t)(t0 + tg * 4 + j) * N_EXP + e] = acc[j];
}

// ---------------- routing: one thread per token, bitmask selection ----------------
// grid: T/64 blocks, 64 threads
__launch_bounds__(64)
__global__ void route_k(const float* __restrict__ sc, const float* __restrict__ gb,
                        float* __restrict__ tw, int* __restrict__ tidx,
                        int* __restrict__ counts) {
  int t = blockIdx.x * 64 + threadIdx.x;
  if (t >= T_TOK) return;
  float orig[N_EXP], sb[N_EXP];
  #pragma unroll
  for (int i = 0; i < N_EXP; i++) {
    float s = 1.f / (1.f + __expf(-sc[(size_t)t * N_EXP + i]));
    orig[i] = s;
    sb[i] = s + gb[i];
  }
  float gsc[8];
  #pragma unroll
  for (int g = 0; g < 8; g++) {
    float m1 = -1e30f, m2 = -1e30f;
    #pragma unroll
    for (int j = 0; j < 4; j++) {
      float v = sb[g * 4 + j];
      if (v > m1) { m2 = m1; m1 = v; } else if (v > m2) m2 = v;
    }
    gsc[g] = m1 + m2;
  }
  unsigned gok = 0;
  #pragma unroll
  for (int it = 0; it < 4; it++) {
    int best = 0; float bv = -1e30f;
    #pragma unroll
    for (int g = 0; g < 8; g++)
      if (!((gok >> g) & 1u) && gsc[g] >= bv) { bv = gsc[g]; best = g; }
    gok |= 1u << best;
  }
  unsigned emask = 0;
  #pragma unroll
  for (int g = 0; g < 8; g++)
    if ((gok >> g) & 1u) emask |= 0xFu << (g * 4);
  unsigned taken = 0;
  int idx[TOPK]; float ow[TOPK]; float wsum = 0.f;
  #pragma unroll
  for (int k = 0; k < TOPK; k++) {
    int best = 0; float bv = -1e30f, bo = 0.f;
    #pragma unroll
    for (int i = 0; i < N_EXP; i++)
      if (((emask >> i) & 1u) && !((taken >> i) & 1u) && sb[i] >= bv) {
        bv = sb[i]; best = i; bo = orig[i];
      }
    taken |= 1u << best;
    idx[k] = best; ow[k] = bo; wsum += bo;
  }
  float inv = 1.f / (wsum + 1e-20f);
  #pragma unroll
  for (int k = 0; k < TOPK; k++) {
    tidx[t * TOPK + k] = idx[k];
    tw[t * TOPK + k] = ow[k] * inv;
    atomicAdd(&counts[idx[k]], 1);
  }
}

__global__ void scan_k(const int* __restrict__ counts, int* __restrict__ offs) {
  if (threadIdx.x == 0 && blockIdx.x == 0) {
    int acc = 0;
    for (int e = 0; e < N_EXP; e++) { offs[e] = acc; acc += counts[e]; }
    offs[N_EXP] = acc;
  }
}

__launch_bounds__(256)
__global__ void scatter_k(const int* __restrict__ tidx, const int* __restrict__ offs,
                          int* __restrict__ fill, int* __restrict__ perm,
                          int* __restrict__ posOf) {
  int t = blockIdx.x * 256 + threadIdx.x;
  if (t >= T_TOK) return;
  for (int j = 0; j < TOPK; j++) {
    int e = tidx[t * TOPK + j];
    int pos = atomicAdd(&fill[e], 1);
    int p = offs[e] + pos;
    perm[p] = t * TOPK + j;
    posOf[t * TOPK + j] = p;
  }
}

// ---------------- final combine ----------------
__launch_bounds__(256)
__global__ void final_gather_k(const float* __restrict__ x1,
                               const unsigned short* __restrict__ dbuf,
                               const unsigned short* __restrict__ sdbuf,
                               const int* __restrict__ posOf,
                               const float* __restrict__ tw,
                               float* __restrict__ out) {
  int t = blockIdx.x;
  int c0 = threadIdx.x * 4;
  int p0 = posOf[t * 4 + 0], p1 = posOf[t * 4 + 1];
  int p2 = posOf[t * 4 + 2], p3 = posOf[t * 4 + 3];
  float w0 = tw[t * 4 + 0], w1 = tw[t * 4 + 1];
  float w2 = tw[t * 4 + 2], w3 = tw[t * 4 + 3];
  size_t tb = (size_t)t * DIM;
  #pragma unroll
  for (int i = 0; i < 4; i++) {
    int c = c0 + i;
    float v = x1[tb + c] + h2f(sdbuf[tb + c])
            + w0 * h2f(dbuf[(size_t)p0 * DIM + c])
            + w1 * h2f(dbuf[(size_t)p1 * DIM + c])
            + w2 * h2f(dbuf[(size_t)p2 * DIM + c])
            + w3 * h2f(dbuf[(size_t)p3 * DIM + c]);
    out[tb + c] = v;
  }
}

// ---------------- host launch ----------------
extern "C" void kernel_launch(void* const* d_in, const int* in_sizes, int n_in,
                              void* d_out, int out_size, void* d_ws, size_t ws_size,
                              hipStream_t stream) {
  const float* x        = (const float*)d_in[0];
  const float* norm_attn= (const float*)d_in[1];
  const float* wq       = (const float*)d_in[2];
  const float* wkv_a    = (const float*)d_in[3];
  const float* kv_norm_w= (const float*)d_in[4];
  const float* wkv_b    = (const float*)d_in[5];
  const float* wo       = (const float*)d_in[6];
  const float* norm_moe = (const float*)d_in[7];
  const float* gate_w   = (const float*)d_in[8];
  const float* gate_b   = (const float*)d_in[9];
  const float* ew1      = (const float*)d_in[10];
  const float* ew2      = (const float*)d_in[11];
  const float* ew3      = (const float*)d_in[12];
  const float* sw1      = (const float*)d_in[13];
  const float* sw2      = (const float*)d_in[14];
  const float* sw3      = (const float*)d_in[15];
  float* out = (float*)d_out;

  char* wp = (char*)d_ws;
  auto alloc = [&](size_t bytes) -> char* {
    char* r = wp;
    wp += (bytes + 255) & ~(size_t)255;
    return r;
  };
  typedef unsigned short us;
  us* wqT   = (us*)alloc(1048576 * 2);
  us* wkvaT = (us*)alloc(327680 * 2);
  us* wkvbT = (us*)alloc(393216 * 2);
  us* woT   = (us*)alloc(1048576 * 2);
  us* ew1T  = (us*)alloc((size_t)16777216 * 2);
  us* ew3T  = (us*)alloc((size_t)16777216 * 2);
  us* ew2T  = (us*)alloc((size_t)16777216 * 2);
  us* sw1T  = (us*)alloc(524288 * 2);
  us* sw3T  = (us*)alloc(524288 * 2);
  us* sw2T  = (us*)alloc(524288 * 2);
  us* xb    = (us*)alloc(2097152 * 2);   // xn, later xfb
  us* cn    = (us*)alloc(524288 * 2);
  us* atn   = (us*)alloc(2097152 * 2);
  us* dbuf  = (us*)alloc((size_t)8388608 * 2);
  us* qb    = (us*)alloc(2097152 * 4);    // f16 q; later sdbuf aliases
  float* kvb  = (float*)alloc(655360 * 4);
  us* kvp   = (us*)alloc(3145728 * 4);    // f16 kvp; later hbuf+hs alias
  float* x1   = (float*)alloc(2097152 * 4);
  float* xf32 = (float*)alloc(2097152 * 4);
  float* scb  = (float*)alloc(65536 * 4);
  float* twb  = (float*)alloc(8192 * 4);
  int* tidx   = (int*)alloc(8192 * 4);
  int* perm   = (int*)alloc(8192 * 4);
  int* posOf  = (int*)alloc(8192 * 4);
  int* counts = (int*)alloc(64 * 4);
  int* offs   = (int*)alloc(64 * 4);
  int* fill   = (int*)alloc(64 * 4);
  us* sdbuf = qb;
  us* hbuf  = kvp;
  us* hs    = hbuf + (size_t)8192 * 512;

  // weight transpose + convert
  tcvt_k<<<dim3(32, 32, 1), 256, 0, stream>>>(wq, wqT, 1024, 1024);
  tcvt_k<<<dim3(10, 32, 1), 256, 0, stream>>>(wkv_a, wkvaT, 1024, 320);
  tcvt_k<<<dim3(48, 8, 1), 256, 0, stream>>>(wkv_b, wkvbT, 256, 1536);
  tcvt_k<<<dim3(32, 32, 1), 256, 0, stream>>>(wo, woT, 1024, 1024);
  tcvt_k<<<dim3(16, 32, 32), 256, 0, stream>>>(ew1, ew1T, 1024, 512);
  tcvt_k<<<dim3(16, 32, 32), 256, 0, stream>>>(ew3, ew3T, 1024, 512);
  tcvt_k<<<dim3(32, 16, 32), 256, 0, stream>>>(ew2, ew2T, 512, 1024);
  tcvt_k<<<dim3(16, 32, 1), 256, 0, stream>>>(sw1, sw1T, 1024, 512);
  tcvt_k<<<dim3(16, 32, 1), 256, 0, stream>>>(sw3, sw3T, 1024, 512);
  tcvt_k<<<dim3(32, 16, 1), 256, 0, stream>>>(sw2, sw2T, 512, 1024);

  // ---- MLA ----
  rmsnorm_k<<<T_TOK, 256, 0, stream>>>(x, DIM, DIM, norm_attn, xb, nullptr, DIM);
  gemm_bt_k<0, 1><<<dim3(16, 32), 256, 0, stream>>>(xb, wqT, nullptr, qb, 1024, 1024);
  gemm_bt_k<0, 0><<<dim3(5, 32), 256, 0, stream>>>(xb, wkvaT, nullptr, kvb, 320, 1024);
  rmsnorm_k<<<T_TOK, 256, 0, stream>>>(kvb, 320, KV_LORA, kv_norm_w, cn, nullptr, KV_LORA);
  gemm_bt_k<0, 1><<<dim3(24, 32), 256, 0, stream>>>(cn, wkvbT, nullptr, kvp, 1536, 256);
  attn_k<<<dim3(S_LEN / 64, HEADS, 2), 256, 0, stream>>>(qb, kvp, kvb, atn);
  gemm_bt_k<1, 0><<<dim3(16, 32), 256, 0, stream>>>(atn, woT, x, x1, 1024, 1024);

  // ---- MoE ----
  rmsnorm_k<<<T_TOK, 256, 0, stream>>>(x1, DIM, DIM, norm_moe, xb, xf32, DIM);
  zero_counters_k<<<1, 64, 0, stream>>>(counts, fill);
  scores_k<<<T_TOK / 32, 256, 0, stream>>>(xf32, gate_w, scb);
  route_k<<<T_TOK / 64, 64, 0, stream>>>(scb, gate_b, twb, tidx, counts);
  scan_k<<<1, 1, 0, stream>>>(counts, offs);
  scatter_k<<<(T_TOK + 255) / 256, 256, 0, stream>>>(tidx, offs, fill, perm, posOf);
  moe_up_k<<<dim3(8, 32, 32), 256, 0, stream>>>(xb, ew1T, ew3T, hbuf, perm, offs, 0);
  moe_down_k<<<dim3(16, 32, 32), 256, 0, stream>>>(hbuf, ew2T, dbuf, offs, 0);
  moe_up_k<<<dim3(8, 32, 1), 256, 0, stream>>>(xb, sw1T, sw3T, hs, nullptr, nullptr, T_TOK);
  moe_down_k<<<dim3(16, 32, 1), 256, 0, stream>>>(hs, sw2T, sdbuf, nullptr, T_TOK);

  final_gather_k<<<T_TOK, 256, 0, stream>>>(x1, dbuf, sdbuf, posOf, twb, out);
}